// Round 2
// 499.164 us; speedup vs baseline: 1.0577x; 1.0577x over previous
//
#include <hip/hip_runtime.h>
#include <hip/hip_bf16.h>
#include <stdint.h>

// Problem constants
#define NB 32
#define NL 256
#define NS 4
#define ND 512
#define NH 1024           // NL * NS
#define FIVE_D 2560
#define HID 2048
#define MMAX 32768        // NB * NS * NL (cap on compact rows)
#define CHUNK 8192        // rows per chunk (workspace ~88 MB)
#define NCHUNK 4

// Inputs: f32 / int32. OUTPUT: f32 (states [B,S,L,D] then mask [B,S,L]).
typedef __bf16 bf16_t;
typedef __bf16 bf16x8 __attribute__((ext_vector_type(8)));
typedef float f32x4 __attribute__((ext_vector_type(4)));

// async global->LDS, 16B per lane (wave-uniform base + lane*16 layout).
__device__ __forceinline__ void async_ld16(const void* g, void* l) {
  __builtin_amdgcn_global_load_lds(
      (__attribute__((address_space(1))) void*)(uintptr_t)g,
      (__attribute__((address_space(3))) void*)(uintptr_t)l, 16, 0, 0);
}

// ---------------------------------------------------------------------------
// K1: build compact row index — PARALLEL version.
// ---------------------------------------------------------------------------
__global__ void build_index_kernel(const int* __restrict__ group_ids,
                                   const int* __restrict__ lengths,
                                   int* __restrict__ n_rows,
                                   int* __restrict__ kept_eff,
                                   int* __restrict__ row_src,
                                   int* __restrict__ row_dst) {
  const int g = blockIdx.x;            // b*NS + s
  const int b = g >> 2, s = g & 3;
  const int t = threadIdx.x;           // 0..255
  const int lane = t & 63, w = t >> 6; // 4 waves
  int len = lengths[b];
  len = len < 0 ? 0 : (len > NH ? NH : len);
  const int* gi = group_ids + b * NH;

  __shared__ int wtot[16];             // per (chunk, wave) match counts
  __shared__ int sbase;

  bool valid[4];
#pragma unroll
  for (int c = 0; c < 4; ++c) {
    int h = c * 256 + t;
    valid[c] = (h < len) && (gi[h] == s + 1);
    unsigned long long m = __ballot(valid[c]);
    if (lane == 0) wtot[c * 4 + w] = __popcll(m);
  }
  __syncthreads();

  int pre[16];
  int run = 0;
#pragma unroll
  for (int i = 0; i < 16; ++i) { pre[i] = run; run += wtot[i]; }
  const int count = run;
  const int keff = count < NL ? count : NL;
  const int offset = count - keff;     // max(count - L, 0)

  if (t == 0) {
    kept_eff[g] = keff;
    sbase = atomicAdd(n_rows, keff);
  }
  __syncthreads();
  const int base = sbase;

  const unsigned long long lt = (1ull << lane) - 1ull;
#pragma unroll
  for (int c = 0; c < 4; ++c) {
    unsigned long long m = __ballot(valid[c]);
    if (valid[c]) {
      int rank = pre[c * 4 + w] + __popcll(m & lt);
      if (rank >= offset) {
        int slot = rank - offset;
        row_src[base + slot] = b * NH + c * 256 + t;
        row_dst[base + slot] = g * NL + slot;
      }
    }
  }
}

// ---------------------------------------------------------------------------
// K2: f32 [K,N] -> bf16 [N,K] tiled transpose (weights).
// ---------------------------------------------------------------------------
template <int KD, int NDIM>
__global__ void transpose_cvt_kernel(const float* __restrict__ src,
                                     bf16_t* __restrict__ dst) {
  __shared__ float tile[32][33];
  int k0 = blockIdx.y * 32, n0 = blockIdx.x * 32;
  int tx = threadIdx.x & 31, ty = threadIdx.x >> 5;   // 32 x 8
#pragma unroll
  for (int i = 0; i < 32; i += 8)
    tile[ty + i][tx] = src[(size_t)(k0 + ty + i) * NDIM + n0 + tx];
  __syncthreads();
#pragma unroll
  for (int i = 0; i < 32; i += 8)
    dst[(size_t)(n0 + ty + i) * KD + k0 + tx] = (bf16_t)tile[tx][ty + i];
}

// ---------------------------------------------------------------------------
// K3: gather 5 f32 embeddings + LayerNorm -> bf16 X[r_local, 2560]
// ---------------------------------------------------------------------------
__global__ void gather_ln_kernel(const float* __restrict__ embed,
                                 const float* __restrict__ tg_emb,
                                 const int* __restrict__ ht,
                                 const int* __restrict__ pt,
                                 const int* __restrict__ at,
                                 const int* __restrict__ ct,
                                 const int* __restrict__ tg,
                                 const float* __restrict__ gamma,
                                 const float* __restrict__ beta,
                                 const int* __restrict__ n_rows,
                                 const int* __restrict__ row_src,
                                 int row_base,
                                 bf16_t* __restrict__ X) {
  int rl = blockIdx.x;
  int r = row_base + rl;
  if (r >= *n_rows) return;
  int pos = row_src[r];
  int t = threadIdx.x;

  const float* seg[5];
  seg[0] = embed + (size_t)ht[pos] * ND;
  seg[1] = embed + (size_t)pt[pos] * ND;
  seg[2] = embed + (size_t)at[pos] * ND;
  seg[3] = embed + (size_t)ct[pos] * ND;
  int tgv = tg[pos];
  tgv = tgv < 0 ? 0 : (tgv > 128 ? 128 : tgv);
  seg[4] = tg_emb + (size_t)tgv * ND;

  float v[10];
  float sum = 0.f, sq = 0.f;
#pragma unroll
  for (int i = 0; i < 10; ++i) {
    int c = t + i * 256;                 // 0..2559; c>>9 constant per i
    v[i] = seg[c >> 9][c & 511];
    sum += v[i];
    sq += v[i] * v[i];
  }
#pragma unroll
  for (int off = 32; off > 0; off >>= 1) {
    sum += __shfl_down(sum, off);
    sq += __shfl_down(sq, off);
  }
  __shared__ float red[8];
  int wv = t >> 6, ln = t & 63;
  if (ln == 0) { red[wv] = sum; red[4 + wv] = sq; }
  __syncthreads();
  float S = red[0] + red[1] + red[2] + red[3];
  float Q = red[4] + red[5] + red[6] + red[7];
  float mu = S * (1.f / FIVE_D);
  float var = Q * (1.f / FIVE_D) - mu * mu;
  float rstd = rsqrtf(var + 1e-5f);

  bf16_t* xr = X + (size_t)rl * FIVE_D;
#pragma unroll
  for (int i = 0; i < 10; ++i) {
    int c = t + i * 256;
    xr[c] = (bf16_t)((v[i] - mu) * rstd * gamma[c] + beta[c]);
  }
}

// ---------------------------------------------------------------------------
// K4a: 256x256 MFMA GEMM, counted-vmcnt double-buffered schedule (plain HIP).
// C[M,N] = A[M,KD] @ Bt[N,KD]^T, epilogue bias+SiLU -> bf16 Cb.
// 512 thr = 8 waves (2M x 4N), BK=64, 128 KiB LDS double-buffer.
//
// RACE FIX vs round 0: the per-quadrant partial-tile vmcnt guarantees were
// invalid (wave wm=1 reads A rows 128..191 = stage half h=1; waves wn>=2 read
// B rows 128..255 = half h=1), so phases consumed LDS before the covering
// loads were guaranteed.  New ledger: ONE counted wait per K-tile that covers
// the ENTIRE previous-staged tile:
//   steady state: 8 loads outstanding (tile c) -> issue 4 A-loads of tile d
//   -> vmcnt(4) retires exactly tile c's 8 -> barrier (join all waves) ->
//   compute quadrants from buf c (full tile guaranteed) -> issue 4 B-loads of
//   tile d mid-compute -> end barrier (reads of c done before tk+1 writes c).
// vmcnt never reaches 0 in the main loop (T4); T2 swizzle + T5 setprio kept.
// ---------------------------------------------------------------------------
#define FENCE asm volatile("" ::: "memory")
#define BARRIER do { FENCE; __builtin_amdgcn_s_barrier(); FENCE; } while (0)
#define WAIT_VM(n) asm volatile("s_waitcnt vmcnt(" #n ")" ::: "memory")
#define WAIT_LGKM do { asm volatile("s_waitcnt lgkmcnt(0)" ::: "memory"); \
                       __builtin_amdgcn_sched_barrier(0); } while (0)

template <int KD, int LDC>
__launch_bounds__(512, 2)
__global__ void gemm256_kernel(const bf16_t* __restrict__ A,
                               const bf16_t* __restrict__ Bt,
                               const int* __restrict__ nrows_p,
                               int row_base,
                               const float* __restrict__ bias,
                               bf16_t* __restrict__ Cb) {
  static_assert(KD % 64 == 0 && KD / 64 >= 2, "KD");
  const int M = *nrows_p;
  const int m0 = blockIdx.y * 256;
  if (row_base + m0 >= M) return;
  const int n0 = blockIdx.x * 256;

  extern __shared__ char smem[];   // [2][ A 32KB | B 32KB ] = 128 KiB

  const int t = threadIdx.x;        // 0..511
  const int lane = t & 63;
  const int wv = t >> 6;            // 0..7
  const int wm = wv >> 2;           // 0..1  (M half)
  const int wn = wv & 3;            // 0..3  (N quarter)
  const int l15 = lane & 15;
  const int l4 = lane >> 4;

  // ---- staging mapping: thread t covers linear LDS chunk t (and t+512).
  // chunk c = row r (c>>3) x 16B-slot q (c&7); slot holds global chunk q^(r&7).
  const int r0 = t >> 3;               // 0..63 (j=1 adds 64 rows: (r&7) same)
  const int sq = (t & 7) ^ (r0 & 7);   // inverse-swizzled global chunk
  const bf16_t* Ab = A + (size_t)(m0 + r0) * KD + sq * 8;
  const bf16_t* Bb = Bt + (size_t)(n0 + r0) * KD + sq * 8;
  const int dst16 = t * 16;

  // ---- ds_read lane offsets (fragment row l15, chunk (ks*4+l4)^(l15&7))
  const int cs0 = (l4 ^ (l15 & 7)) << 4;   // ks=0 swizzled byte slot
  const int cs1 = cs0 ^ 64;                // ks=1
  const int arow = (wm * 128 + l15) * 128; // A row byte base for this wave
  const int brow = (wn * 64 + l15) * 128;  // B row byte base

  f32x4 acc[2][2][4][2] = {};              // [mh][nh][i][jj]
  bf16x8 a[4][2], bl[2][2], bh[2][2];

#define STAGE_A(dbuf, h, kofs)                                               \
  do {                                                                       \
    char* _d = smem + (dbuf) * 65536 + (h) * 16384 + dst16;                  \
    async_ld16(Ab + (size_t)((h) * 128) * KD + (kofs), _d);                  \
    async_ld16(Ab + (size_t)((h) * 128 + 64) * KD + (kofs), _d + 8192);      \
  } while (0)
#define STAGE_B(dbuf, h, kofs)                                               \
  do {                                                                       \
    char* _d = smem + (dbuf) * 65536 + 32768 + (h) * 16384 + dst16;          \
    async_ld16(Bb + (size_t)((h) * 128) * KD + (kofs), _d);                  \
    async_ld16(Bb + (size_t)((h) * 128 + 64) * KD + (kofs), _d + 8192);      \
  } while (0)
#define LOAD_A(cbuf, mh)                                                     \
  do {                                                                       \
    const char* _s = smem + (cbuf) * 65536 + (mh) * 8192 + arow;             \
    _Pragma("unroll") for (int _i = 0; _i < 4; ++_i) {                       \
      a[_i][0] = *(const bf16x8*)(_s + _i * 2048 + cs0);                     \
      a[_i][1] = *(const bf16x8*)(_s + _i * 2048 + cs1);                     \
    }                                                                        \
  } while (0)
#define LOAD_B(dst, cbuf, nh)                                                \
  do {                                                                       \
    const char* _s = smem + (cbuf) * 65536 + 32768 + (nh) * 4096 + brow;     \
    _Pragma("unroll") for (int _j = 0; _j < 2; ++_j) {                       \
      dst[_j][0] = *(const bf16x8*)(_s + _j * 2048 + cs0);                   \
      dst[_j][1] = *(const bf16x8*)(_s + _j * 2048 + cs1);                   \
    }                                                                        \
  } while (0)
#define MMA(mh, nh, B)                                                       \
  do {                                                                       \
    _Pragma("unroll") for (int _i = 0; _i < 4; ++_i)                         \
    _Pragma("unroll") for (int _j = 0; _j < 2; ++_j) {                       \
      acc[mh][nh][_i][_j] = __builtin_amdgcn_mfma_f32_16x16x32_bf16(         \
          a[_i][0], B[_j][0], acc[mh][nh][_i][_j], 0, 0, 0);                 \
      acc[mh][nh][_i][_j] = __builtin_amdgcn_mfma_f32_16x16x32_bf16(         \
          a[_i][1], B[_j][1], acc[mh][nh][_i][_j], 0, 0, 0);                 \
    }                                                                        \
  } while (0)

  constexpr int NT = KD / 64;

  // prologue: stage tile 0 into buf 0 (8 loads: Alo, Ahi, Blo, Bhi)
  STAGE_A(0, 0, 0);
  STAGE_A(0, 1, 0);
  STAGE_B(0, 0, 0);
  STAGE_B(0, 1, 0);

  int c = 0;
  for (int tk = 1; tk < NT; ++tk) {  // compute tile tk-1 (buf c), stage tk
    const int kn = tk * 64;
    const int d = c ^ 1;
    // stage A-halves of next tile: outstanding 8 -> 12
    STAGE_A(d, 0, kn);
    STAGE_A(d, 1, kn);
    WAIT_VM(4);      // retire exactly the previous tile's 8 loads (this wave)
    BARRIER;         // join: ALL waves' tile-c loads have landed in LDS
    // quadrant (m-lo, n-lo)
    LOAD_A(c, 0);
    LOAD_B(bl, c, 0);
    WAIT_LGKM;
    __builtin_amdgcn_s_setprio(1);
    MMA(0, 0, bl);
    __builtin_amdgcn_s_setprio(0);
    // quadrant (m-lo, n-hi)
    LOAD_B(bh, c, 1);
    WAIT_LGKM;
    __builtin_amdgcn_s_setprio(1);
    MMA(0, 1, bh);
    __builtin_amdgcn_s_setprio(0);
    // stage B-halves of next tile mid-compute: outstanding 4 -> 8
    STAGE_B(d, 0, kn);
    STAGE_B(d, 1, kn);
    // quadrants (m-hi, n-hi) and (m-hi, n-lo)
    LOAD_A(c, 1);
    WAIT_LGKM;
    __builtin_amdgcn_s_setprio(1);
    MMA(1, 1, bh);
    MMA(1, 0, bl);
    __builtin_amdgcn_s_setprio(0);
    BARRIER;         // WAR: all reads of buf c done before tk+1 writes buf c
    c = d;
  }

  // peeled last tile: its 8 loads are the only outstanding ones
  WAIT_VM(0);
  BARRIER;
  LOAD_A(c, 0);
  LOAD_B(bl, c, 0);
  WAIT_LGKM;
  MMA(0, 0, bl);
  LOAD_B(bh, c, 1);
  WAIT_LGKM;
  MMA(0, 1, bh);
  LOAD_A(c, 1);
  WAIT_LGKM;
  MMA(1, 1, bh);
  MMA(1, 0, bl);

  // epilogue: bias + SiLU -> bf16 (rows beyond M are garbage; GEMM2 guards)
#pragma unroll
  for (int mh = 0; mh < 2; ++mh)
#pragma unroll
    for (int i = 0; i < 4; ++i) {
      const int rbase = m0 + wm * 128 + mh * 64 + i * 16 + l4 * 4;
#pragma unroll
      for (int nh = 0; nh < 2; ++nh)
#pragma unroll
        for (int j = 0; j < 2; ++j) {
          const int n = n0 + wn * 64 + nh * 32 + j * 16 + l15;
          const float bn = bias[n];
#pragma unroll
          for (int q = 0; q < 4; ++q) {
            float v = acc[mh][nh][i][j][q] + bn;
            v = v / (1.f + __expf(-v));              // SiLU
            Cb[(size_t)(rbase + q) * LDC + n] = (bf16_t)v;
          }
        }
    }
#undef STAGE_A
#undef STAGE_B
#undef LOAD_A
#undef LOAD_B
#undef MMA
}

// ---------------------------------------------------------------------------
// K4b: m97-structure 128x128 GEMM, kept for GEMM2 (N=512: a 256-wide tile
// would leave 3/4 of the CUs idle). EPI=2: +bias +pos_emb +seq_emb scatter.
// ---------------------------------------------------------------------------
template <int KD, int LDC, int EPI>
__launch_bounds__(256)
__global__ void gemm_kernel(const bf16_t* __restrict__ A,
                            const bf16_t* __restrict__ Bt,
                            const int* __restrict__ nrows_p,
                            int row_base,
                            const float* __restrict__ bias,
                            bf16_t* __restrict__ Cb,
                            const int* __restrict__ row_dst,
                            const float* __restrict__ pos_emb,
                            const float* __restrict__ seq_emb,
                            float* __restrict__ out) {
  const int M = *nrows_p;
  const int m0 = blockIdx.y * 128;                 // local row base
  if (row_base + m0 >= M) return;
  const int n0 = blockIdx.x * 128;

  __shared__ bf16_t As[128 * 32];
  __shared__ bf16_t Bs[128 * 32];

  const int t = threadIdx.x;
  const int lane = t & 63;
  const int wave = t >> 6;
  const int wm = wave >> 1;
  const int wn = wave & 1;
  const int l15 = lane & 15;
  const int l4 = lane >> 4;

  f32x4 acc[4][4] = {};

  const int r0 = t >> 2;            // tile row for this thread's 16B segment
  const int kq = (t & 3) * 8;       // bf16 offset within 32-wide k window
  const bf16_t* Ag0 = A + (size_t)(m0 + r0) * KD + kq;
  const bf16_t* Ag1 = A + (size_t)(m0 + 64 + r0) * KD + kq;
  const bf16_t* Bg0 = Bt + (size_t)(n0 + r0) * KD + kq;
  const bf16_t* Bg1 = Bt + (size_t)(n0 + 64 + r0) * KD + kq;
  bf16_t* Al0 = As + t * 8;
  bf16_t* Al1 = As + (t + 256) * 8;
  bf16_t* Bl0 = Bs + t * 8;
  bf16_t* Bl1 = Bs + (t + 256) * 8;

  for (int k0 = 0; k0 < KD; k0 += 32) {
    __syncthreads();
    async_ld16(Ag0 + k0, Al0);
    async_ld16(Ag1 + k0, Al1);
    async_ld16(Bg0 + k0, Bl0);
    async_ld16(Bg1 + k0, Bl1);
    __syncthreads();

    bf16x8 af[4], bfr[4];
#pragma unroll
    for (int i = 0; i < 4; ++i)
      af[i] = *(const bf16x8*)(As + (wm * 64 + i * 16 + l15) * 32 + l4 * 8);
#pragma unroll
    for (int i = 0; i < 4; ++i)
      bfr[i] = *(const bf16x8*)(Bs + (wn * 64 + i * 16 + l15) * 32 + l4 * 8);
#pragma unroll
    for (int i = 0; i < 4; ++i)
#pragma unroll
      for (int j = 0; j < 4; ++j)
        acc[i][j] =
            __builtin_amdgcn_mfma_f32_16x16x32_bf16(af[i], bfr[j], acc[i][j], 0, 0, 0);
  }

  if constexpr (EPI == 1) {
#pragma unroll
    for (int i = 0; i < 4; ++i) {
      int mbase = m0 + wm * 64 + i * 16 + l4 * 4;   // local row
#pragma unroll
      for (int j = 0; j < 4; ++j) {
        int n = n0 + wn * 64 + j * 16 + l15;
        float bn = bias[n];
#pragma unroll
        for (int q = 0; q < 4; ++q) {
          float v = acc[i][j][q] + bn;
          v = v / (1.f + __expf(-v));              // SiLU
          Cb[(size_t)(mbase + q) * LDC + n] = (bf16_t)v;
        }
      }
    }
  } else {
#pragma unroll
    for (int i = 0; i < 4; ++i) {
      int mbase = m0 + wm * 64 + i * 16 + l4 * 4;   // local row
#pragma unroll
      for (int q = 0; q < 4; ++q) {
        int r = mbase + q;                          // local row
        if (row_base + r >= M) continue;
        int dst = row_dst[row_base + r];            // (b*S+s)*L + slot
        int slot = dst & (NL - 1);
        int sg = (dst >> 8) & 3;
#pragma unroll
        for (int j = 0; j < 4; ++j) {
          int n = n0 + wn * 64 + j * 16 + l15;
          float v = acc[i][j][q] + bias[n] + pos_emb[slot * ND + n] +
                    seq_emb[(sg + 1) * ND + n];
          out[(size_t)dst * ND + n] = v;            // f32 output
        }
      }
    }
  }
}

// ---------------------------------------------------------------------------
// K5: background fill (f32) — zeros for unkept slots, empty-group slot 0,
// and the f32 sequence mask. One block per (b, s).
// ---------------------------------------------------------------------------
__global__ void fill_bg_kernel(const int* __restrict__ kept_eff,
                               const float* __restrict__ empty_tokens,
                               const float* __restrict__ pos_emb,
                               const float* __restrict__ seq_emb,
                               float* __restrict__ out,
                               float* __restrict__ mask) {
  int g = blockIdx.x;              // b*S + s
  int s = g & 3;
  int t = threadIdx.x;
  int ce = kept_eff[g];            // min(count, L)
  bool empty = (ce == 0);
  int keptm = empty ? 1 : ce;

  mask[g * NL + t] = (t < keptm) ? 1.f : 0.f;      // t in [0,256)=L

  float* base = out + (size_t)g * NL * ND;
  if (empty) {
    for (int d = t; d < ND; d += 256)
      base[d] = empty_tokens[s * ND + d] + pos_emb[d] + seq_emb[(s + 1) * ND + d];
  }
  int start = empty ? 1 : ce;
  // zero-fill slots [start, 256) with 16B stores
  uint4* p = (uint4*)base;         // 4 f32 per uint4; one slot = 128 uint4
  uint4 z; z.x = z.y = z.z = z.w = 0u;
  for (int i = start * (ND / 4) + t; i < NL * (ND / 4); i += 256) p[i] = z;
}

// ---------------------------------------------------------------------------
extern "C" void kernel_launch(void* const* d_in, const int* in_sizes, int n_in,
                              void* d_out, int out_size, void* d_ws,
                              size_t ws_size, hipStream_t stream) {
  const float* embed_table = (const float*)d_in[0];
  const float* time_gap_emb = (const float*)d_in[1];
  const float* seq_id_emb = (const float*)d_in[2];
  const float* pos_emb = (const float*)d_in[3];
  const float* ln_gamma = (const float*)d_in[4];
  const float* ln_beta = (const float*)d_in[5];
  const float* w1 = (const float*)d_in[6];
  const float* b1 = (const float*)d_in[7];
  const float* w2 = (const float*)d_in[8];
  const float* b2 = (const float*)d_in[9];
  const float* empty_tokens = (const float*)d_in[10];
  const int* history_tokens = (const int*)d_in[11];
  const int* post_tokens = (const int*)d_in[12];
  const int* author_tokens = (const int*)d_in[13];
  const int* action_tokens = (const int*)d_in[14];
  const int* time_gap = (const int*)d_in[15];
  const int* group_ids = (const int*)d_in[16];
  const int* lengths = (const int*)d_in[17];

  // Workspace (~88 MB peak)
  char* ws = (char*)d_ws;
  int* n_rows = (int*)ws;                                  // 4 B
  int* kept_eff = (int*)(ws + 256);                        // 128*4 B
  int* row_src = (int*)(ws + 4096);                        // 32768*4 B
  int* row_dst = (int*)(ws + 4096 + 131072);               // 32768*4 B
  bf16_t* W1T = (bf16_t*)(ws + 266240);                    // [2048][2560] bf16
  bf16_t* W2T = W1T + (size_t)HID * FIVE_D;                // [512][2048]  bf16
  bf16_t* Xc = W2T + (size_t)ND * HID;                     // [CHUNK][2560] bf16
  bf16_t* H1c = Xc + (size_t)CHUNK * FIVE_D;               // [CHUNK][2048] bf16

  float* out_states = (float*)d_out;                       // f32 output
  float* out_mask = out_states + (size_t)NB * NS * NL * ND;

  // 128 KiB dynamic LDS opt-in for the 256^2 GEMM.  Host-side, idempotent,
  // called unconditionally every launch (no call-count-dependent branching).
  (void)hipFuncSetAttribute(
      reinterpret_cast<const void*>(gemm256_kernel<FIVE_D, HID>),
      hipFuncAttributeMaxDynamicSharedMemorySize, 131072);

  // n_rows must start at 0 (ws is poisoned 0xAA before every launch).
  hipMemsetAsync(n_rows, 0, 4, stream);

  build_index_kernel<<<NB * NS, 256, 0, stream>>>(group_ids, lengths, n_rows,
                                                  kept_eff, row_src, row_dst);

  transpose_cvt_kernel<FIVE_D, HID>
      <<<dim3(HID / 32, FIVE_D / 32), 256, 0, stream>>>(w1, W1T);
  transpose_cvt_kernel<HID, ND>
      <<<dim3(ND / 32, HID / 32), 256, 0, stream>>>(w2, W2T);

  for (int c = 0; c < NCHUNK; ++c) {
    int row_base = c * CHUNK;
    gather_ln_kernel<<<CHUNK, 256, 0, stream>>>(
        embed_table, time_gap_emb, history_tokens, post_tokens, author_tokens,
        action_tokens, time_gap, ln_gamma, ln_beta, n_rows, row_src, row_base,
        Xc);

    gemm256_kernel<FIVE_D, HID>
        <<<dim3(HID / 256, CHUNK / 256), 512, 131072, stream>>>(
            Xc, W1T, n_rows, row_base, b1, H1c);

    gemm_kernel<HID, ND, 2>
        <<<dim3(ND / 128, CHUNK / 128), 256, 0, stream>>>(
            H1c, W2T, n_rows, row_base, b2, nullptr, row_dst, pos_emb,
            seq_id_emb, out_states);
  }

  fill_bg_kernel<<<NB * NS, 256, 0, stream>>>(kept_eff, empty_tokens, pos_emb,
                                              seq_id_emb, out_states, out_mask);
}

// Round 3
// 473.856 us; speedup vs baseline: 1.1142x; 1.0534x over previous
//
#include <hip/hip_runtime.h>
#include <hip/hip_bf16.h>
#include <stdint.h>

// Problem constants
#define NB 32
#define NL 256
#define NS 4
#define ND 512
#define NH 1024           // NL * NS
#define FIVE_D 2560
#define HID 2048
#define MMAX 32768        // NB * NS * NL (cap on compact rows)
#define CHUNK 8192        // rows per chunk (workspace ~88 MB)
#define NCHUNK 4

// Inputs: f32 / int32. OUTPUT: f32 (states [B,S,L,D] then mask [B,S,L]).
typedef __bf16 bf16_t;
typedef __bf16 bf16x8 __attribute__((ext_vector_type(8)));
typedef float f32x4 __attribute__((ext_vector_type(4)));

// async global->LDS, 16B per lane (wave-uniform base + lane*16 layout).
__device__ __forceinline__ void async_ld16(const void* g, void* l) {
  __builtin_amdgcn_global_load_lds(
      (__attribute__((address_space(1))) void*)(uintptr_t)g,
      (__attribute__((address_space(3))) void*)(uintptr_t)l, 16, 0, 0);
}

// ---------------------------------------------------------------------------
// K1: build compact row index — PARALLEL version.
// ---------------------------------------------------------------------------
__global__ void build_index_kernel(const int* __restrict__ group_ids,
                                   const int* __restrict__ lengths,
                                   int* __restrict__ n_rows,
                                   int* __restrict__ kept_eff,
                                   int* __restrict__ row_src,
                                   int* __restrict__ row_dst) {
  const int g = blockIdx.x;            // b*NS + s
  const int b = g >> 2, s = g & 3;
  const int t = threadIdx.x;           // 0..255
  const int lane = t & 63, w = t >> 6; // 4 waves
  int len = lengths[b];
  len = len < 0 ? 0 : (len > NH ? NH : len);
  const int* gi = group_ids + b * NH;

  __shared__ int wtot[16];             // per (chunk, wave) match counts
  __shared__ int sbase;

  bool valid[4];
#pragma unroll
  for (int c = 0; c < 4; ++c) {
    int h = c * 256 + t;
    valid[c] = (h < len) && (gi[h] == s + 1);
    unsigned long long m = __ballot(valid[c]);
    if (lane == 0) wtot[c * 4 + w] = __popcll(m);
  }
  __syncthreads();

  int pre[16];
  int run = 0;
#pragma unroll
  for (int i = 0; i < 16; ++i) { pre[i] = run; run += wtot[i]; }
  const int count = run;
  const int keff = count < NL ? count : NL;
  const int offset = count - keff;     // max(count - L, 0)

  if (t == 0) {
    kept_eff[g] = keff;
    sbase = atomicAdd(n_rows, keff);
  }
  __syncthreads();
  const int base = sbase;

  const unsigned long long lt = (1ull << lane) - 1ull;
#pragma unroll
  for (int c = 0; c < 4; ++c) {
    unsigned long long m = __ballot(valid[c]);
    if (valid[c]) {
      int rank = pre[c * 4 + w] + __popcll(m & lt);
      if (rank >= offset) {
        int slot = rank - offset;
        row_src[base + slot] = b * NH + c * 256 + t;
        row_dst[base + slot] = g * NL + slot;
      }
    }
  }
}

// ---------------------------------------------------------------------------
// K2: f32 [K,N] -> bf16 [N,K] tiled transpose (weights).
// ---------------------------------------------------------------------------
template <int KD, int NDIM>
__global__ void transpose_cvt_kernel(const float* __restrict__ src,
                                     bf16_t* __restrict__ dst) {
  __shared__ float tile[32][33];
  int k0 = blockIdx.y * 32, n0 = blockIdx.x * 32;
  int tx = threadIdx.x & 31, ty = threadIdx.x >> 5;   // 32 x 8
#pragma unroll
  for (int i = 0; i < 32; i += 8)
    tile[ty + i][tx] = src[(size_t)(k0 + ty + i) * NDIM + n0 + tx];
  __syncthreads();
#pragma unroll
  for (int i = 0; i < 32; i += 8)
    dst[(size_t)(n0 + ty + i) * KD + k0 + tx] = (bf16_t)tile[tx][ty + i];
}

// ---------------------------------------------------------------------------
// K3: gather 5 f32 embeddings + LayerNorm -> bf16 X[r_local, 2560]
// ---------------------------------------------------------------------------
__global__ void gather_ln_kernel(const float* __restrict__ embed,
                                 const float* __restrict__ tg_emb,
                                 const int* __restrict__ ht,
                                 const int* __restrict__ pt,
                                 const int* __restrict__ at,
                                 const int* __restrict__ ct,
                                 const int* __restrict__ tg,
                                 const float* __restrict__ gamma,
                                 const float* __restrict__ beta,
                                 const int* __restrict__ n_rows,
                                 const int* __restrict__ row_src,
                                 int row_base,
                                 bf16_t* __restrict__ X) {
  int rl = blockIdx.x;
  int r = row_base + rl;
  if (r >= *n_rows) return;
  int pos = row_src[r];
  int t = threadIdx.x;

  const float* seg[5];
  seg[0] = embed + (size_t)ht[pos] * ND;
  seg[1] = embed + (size_t)pt[pos] * ND;
  seg[2] = embed + (size_t)at[pos] * ND;
  seg[3] = embed + (size_t)ct[pos] * ND;
  int tgv = tg[pos];
  tgv = tgv < 0 ? 0 : (tgv > 128 ? 128 : tgv);
  seg[4] = tg_emb + (size_t)tgv * ND;

  float v[10];
  float sum = 0.f, sq = 0.f;
#pragma unroll
  for (int i = 0; i < 10; ++i) {
    int c = t + i * 256;                 // 0..2559; c>>9 constant per i
    v[i] = seg[c >> 9][c & 511];
    sum += v[i];
    sq += v[i] * v[i];
  }
#pragma unroll
  for (int off = 32; off > 0; off >>= 1) {
    sum += __shfl_down(sum, off);
    sq += __shfl_down(sq, off);
  }
  __shared__ float red[8];
  int wv = t >> 6, ln = t & 63;
  if (ln == 0) { red[wv] = sum; red[4 + wv] = sq; }
  __syncthreads();
  float S = red[0] + red[1] + red[2] + red[3];
  float Q = red[4] + red[5] + red[6] + red[7];
  float mu = S * (1.f / FIVE_D);
  float var = Q * (1.f / FIVE_D) - mu * mu;
  float rstd = rsqrtf(var + 1e-5f);

  bf16_t* xr = X + (size_t)rl * FIVE_D;
#pragma unroll
  for (int i = 0; i < 10; ++i) {
    int c = t + i * 256;
    xr[c] = (bf16_t)((v[i] - mu) * rstd * gamma[c] + beta[c]);
  }
}

// ---------------------------------------------------------------------------
// Shared sync macros (verified v3 ledger: one counted wait per K-tile that
// covers the ENTIRE previous-staged tile; all loads of tile d issued at the
// TOP of tile c's compute, so each gets a full-tile (~1500 cy) latency cover.
//   steady state: 8 outstanding (tile c) -> issue tile d's 8 -> vmcnt(8)
//   retires exactly tile c's 8 -> barrier -> compute from buf c -> barrier
//   (WAR: reads of c done before next iter writes c).
// vmcnt never reaches 0 in the main loop (T4); T2 swizzle + T5 setprio kept.
// ---------------------------------------------------------------------------
#define FENCE asm volatile("" ::: "memory")
#define BARRIER do { FENCE; __builtin_amdgcn_s_barrier(); FENCE; } while (0)
#define WAIT_VM(n) asm volatile("s_waitcnt vmcnt(" #n ")" ::: "memory")
#define WAIT_LGKM do { asm volatile("s_waitcnt lgkmcnt(0)" ::: "memory"); \
                       __builtin_amdgcn_sched_barrier(0); } while (0)

// ---------------------------------------------------------------------------
// K4a: 256x256 MFMA GEMM, counted-vmcnt double-buffered schedule (plain HIP).
// C[M,N] = A[M,KD] @ Bt[N,KD]^T, epilogue bias+SiLU -> bf16 Cb.
// 512 thr = 8 waves (2M x 4N), BK=64, 128 KiB LDS double-buffer.
// ---------------------------------------------------------------------------
template <int KD, int LDC>
__launch_bounds__(512, 2)
__global__ void gemm256_kernel(const bf16_t* __restrict__ A,
                               const bf16_t* __restrict__ Bt,
                               const int* __restrict__ nrows_p,
                               int row_base,
                               const float* __restrict__ bias,
                               bf16_t* __restrict__ Cb) {
  static_assert(KD % 64 == 0 && KD / 64 >= 2, "KD");
  const int M = *nrows_p;
  const int m0 = blockIdx.y * 256;
  if (row_base + m0 >= M) return;
  const int n0 = blockIdx.x * 256;

  extern __shared__ char smem[];   // [2][ A 32KB | B 32KB ] = 128 KiB

  const int t = threadIdx.x;        // 0..511
  const int lane = t & 63;
  const int wv = t >> 6;            // 0..7
  const int wm = wv >> 2;           // 0..1  (M half)
  const int wn = wv & 3;            // 0..3  (N quarter)
  const int l15 = lane & 15;
  const int l4 = lane >> 4;

  // ---- staging mapping: thread t covers linear LDS chunk t (and t+512).
  // chunk c = row r (c>>3) x 16B-slot q (c&7); slot holds global chunk q^(r&7).
  const int r0 = t >> 3;               // 0..63 (j=1 adds 64 rows: (r&7) same)
  const int sq = (t & 7) ^ (r0 & 7);   // inverse-swizzled global chunk
  const bf16_t* Ab = A + (size_t)(m0 + r0) * KD + sq * 8;
  const bf16_t* Bb = Bt + (size_t)(n0 + r0) * KD + sq * 8;
  const int dst16 = t * 16;

  // ---- ds_read lane offsets (fragment row l15, chunk (ks*4+l4)^(l15&7))
  const int cs0 = (l4 ^ (l15 & 7)) << 4;   // ks=0 swizzled byte slot
  const int cs1 = cs0 ^ 64;                // ks=1
  const int arow = (wm * 128 + l15) * 128; // A row byte base for this wave
  const int brow = (wn * 64 + l15) * 128;  // B row byte base

  f32x4 acc[2][2][4][2] = {};              // [mh][nh][i][jj]
  bf16x8 a[4][2], bl[2][2], bh[2][2];

#define STAGE_A(dbuf, h, kofs)                                               \
  do {                                                                       \
    char* _d = smem + (dbuf) * 65536 + (h) * 16384 + dst16;                  \
    async_ld16(Ab + (size_t)((h) * 128) * KD + (kofs), _d);                  \
    async_ld16(Ab + (size_t)((h) * 128 + 64) * KD + (kofs), _d + 8192);      \
  } while (0)
#define STAGE_B(dbuf, h, kofs)                                               \
  do {                                                                       \
    char* _d = smem + (dbuf) * 65536 + 32768 + (h) * 16384 + dst16;          \
    async_ld16(Bb + (size_t)((h) * 128) * KD + (kofs), _d);                  \
    async_ld16(Bb + (size_t)((h) * 128 + 64) * KD + (kofs), _d + 8192);      \
  } while (0)
#define LOAD_A(cbuf, mh)                                                     \
  do {                                                                       \
    const char* _s = smem + (cbuf) * 65536 + (mh) * 8192 + arow;             \
    _Pragma("unroll") for (int _i = 0; _i < 4; ++_i) {                       \
      a[_i][0] = *(const bf16x8*)(_s + _i * 2048 + cs0);                     \
      a[_i][1] = *(const bf16x8*)(_s + _i * 2048 + cs1);                     \
    }                                                                        \
  } while (0)
#define LOAD_B(dst, cbuf, nh)                                                \
  do {                                                                       \
    const char* _s = smem + (cbuf) * 65536 + 32768 + (nh) * 4096 + brow;     \
    _Pragma("unroll") for (int _j = 0; _j < 2; ++_j) {                       \
      dst[_j][0] = *(const bf16x8*)(_s + _j * 2048 + cs0);                   \
      dst[_j][1] = *(const bf16x8*)(_s + _j * 2048 + cs1);                   \
    }                                                                        \
  } while (0)
#define MMA(mh, nh, B)                                                       \
  do {                                                                       \
    _Pragma("unroll") for (int _i = 0; _i < 4; ++_i)                         \
    _Pragma("unroll") for (int _j = 0; _j < 2; ++_j) {                       \
      acc[mh][nh][_i][_j] = __builtin_amdgcn_mfma_f32_16x16x32_bf16(         \
          a[_i][0], B[_j][0], acc[mh][nh][_i][_j], 0, 0, 0);                 \
      acc[mh][nh][_i][_j] = __builtin_amdgcn_mfma_f32_16x16x32_bf16(         \
          a[_i][1], B[_j][1], acc[mh][nh][_i][_j], 0, 0, 0);                 \
    }                                                                        \
  } while (0)

  constexpr int NT = KD / 64;

  // prologue: stage tile 0 into buf 0 (8 loads: Alo, Ahi, Blo, Bhi)
  STAGE_A(0, 0, 0);
  STAGE_A(0, 1, 0);
  STAGE_B(0, 0, 0);
  STAGE_B(0, 1, 0);

  int c = 0;
  for (int tk = 1; tk < NT; ++tk) {  // compute tile tk-1 (buf c), stage tk
    const int kn = tk * 64;
    const int d = c ^ 1;
    // stage ALL of next tile at the top: outstanding 8 -> 16.  Full-tile
    // latency cover for every load (round-2 issued B mid-compute: ~half the
    // cover, and the vmcnt(4) wait ate ~900 cy/tile -> MfmaUtil 41%).
    STAGE_A(d, 0, kn);
    STAGE_A(d, 1, kn);
    STAGE_B(d, 0, kn);
    STAGE_B(d, 1, kn);
    WAIT_VM(8);      // retire exactly the previous tile's 8 loads (this wave)
    BARRIER;         // join: ALL waves' tile-c loads have landed in LDS
    // quadrant (m-lo, n-lo)
    LOAD_A(c, 0);
    LOAD_B(bl, c, 0);
    WAIT_LGKM;
    __builtin_amdgcn_s_setprio(1);
    MMA(0, 0, bl);
    __builtin_amdgcn_s_setprio(0);
    // quadrant (m-lo, n-hi)
    LOAD_B(bh, c, 1);
    WAIT_LGKM;
    __builtin_amdgcn_s_setprio(1);
    MMA(0, 1, bh);
    __builtin_amdgcn_s_setprio(0);
    // quadrants (m-hi, n-hi) and (m-hi, n-lo)
    LOAD_A(c, 1);
    WAIT_LGKM;
    __builtin_amdgcn_s_setprio(1);
    MMA(1, 1, bh);
    MMA(1, 0, bl);
    __builtin_amdgcn_s_setprio(0);
    BARRIER;         // WAR: all reads of buf c done before tk+1 writes buf c
    c = d;
  }

  // peeled last tile: its 8 loads are the only outstanding ones
  WAIT_VM(0);
  BARRIER;
  LOAD_A(c, 0);
  LOAD_B(bl, c, 0);
  WAIT_LGKM;
  MMA(0, 0, bl);
  LOAD_B(bh, c, 1);
  WAIT_LGKM;
  MMA(0, 1, bh);
  LOAD_A(c, 1);
  WAIT_LGKM;
  MMA(1, 1, bh);
  MMA(1, 0, bl);

  // epilogue: bias + SiLU -> bf16 (rows beyond M are garbage; GEMM2 guards)
#pragma unroll
  for (int mh = 0; mh < 2; ++mh)
#pragma unroll
    for (int i = 0; i < 4; ++i) {
      const int rbase = m0 + wm * 128 + mh * 64 + i * 16 + l4 * 4;
#pragma unroll
      for (int nh = 0; nh < 2; ++nh)
#pragma unroll
        for (int j = 0; j < 2; ++j) {
          const int n = n0 + wn * 64 + nh * 32 + j * 16 + l15;
          const float bn = bias[n];
#pragma unroll
          for (int q = 0; q < 4; ++q) {
            float v = acc[mh][nh][i][j][q] + bn;
            v = v / (1.f + __expf(-v));              // SiLU
            Cb[(size_t)(rbase + q) * LDC + n] = (bf16_t)v;
          }
        }
    }
#undef STAGE_A
#undef STAGE_B
#undef LOAD_A
#undef LOAD_B
#undef MMA
}

// ---------------------------------------------------------------------------
// K4b: 128x128 MFMA GEMM for GEMM2 (N=512), same v3 counted-vmcnt ledger.
// 512 thr = 8 waves (4M x 2N), per-wave 32x64 output, BK=64, 64 KiB LDS
// double-buffer.  Rows are 128 B (64 bf16) exactly like gemm256, so the
// identical st-swizzle math applies (q ^= r&7 per 16B chunk, both sides).
// Epilogue: +bias +pos_emb +seq_emb, scatter f32 rows via row_dst (math
// identical to the previous m97-structure EPI=2; only wave->subtile mapping
// re-derived for the 4x2 wave grid).
// Replaces the m97 2-barrier vmcnt(0)-per-32-K-step loop (64 full drains).
// ---------------------------------------------------------------------------
template <int KD>
__launch_bounds__(512, 2)
__global__ void gemm128_scatter_kernel(const bf16_t* __restrict__ A,
                                       const bf16_t* __restrict__ Bt,
                                       const int* __restrict__ nrows_p,
                                       int row_base,
                                       const float* __restrict__ bias,
                                       const int* __restrict__ row_dst,
                                       const float* __restrict__ pos_emb,
                                       const float* __restrict__ seq_emb,
                                       float* __restrict__ out) {
  static_assert(KD % 64 == 0 && KD / 64 >= 2, "KD");
  const int M = *nrows_p;
  const int m0 = blockIdx.y * 128;
  if (row_base + m0 >= M) return;
  const int n0 = blockIdx.x * 128;

  extern __shared__ char smem[];   // [2][ A 16KB | B 16KB ] = 64 KiB

  const int t = threadIdx.x;        // 0..511
  const int lane = t & 63;
  const int wv = t >> 6;            // 0..7
  const int wm = wv >> 1;           // 0..3  (M quarter, 32 rows)
  const int wn = wv & 1;            // 0..1  (N half, 64 cols)
  const int l15 = lane & 15;
  const int l4 = lane >> 4;

  // staging: thread t covers linear LDS chunk t (rows 0..63) and t+512
  // (rows 64..127); chunk c = row (c>>3) x slot (c&7); slot q holds global
  // chunk q^(r&7).  (r+64)&7 == r&7, so sq is constant across both issues.
  const int r0 = t >> 3;               // 0..63
  const int sq = (t & 7) ^ (r0 & 7);
  const bf16_t* Ab = A + (size_t)(m0 + r0) * KD + sq * 8;
  const bf16_t* Bb = Bt + (size_t)(n0 + r0) * KD + sq * 8;
  const int dst16 = t * 16;

  const int cs0 = (l4 ^ (l15 & 7)) << 4;   // ks=0 swizzled byte slot
  const int cs1 = cs0 ^ 64;                // ks=1
  const int arow = (wm * 32 + l15) * 128;  // A row byte base for this wave
  const int brow = (wn * 64 + l15) * 128;  // B row byte base

  f32x4 acc[2][4] = {};                    // [i (16-row frag)][j (16-col frag)]
  bf16x8 a[2][2], b[4][2];

#define STAGE_A2(dbuf, kofs)                                                 \
  do {                                                                       \
    char* _d = smem + (dbuf) * 32768 + dst16;                                \
    async_ld16(Ab + (kofs), _d);                                             \
    async_ld16(Ab + (size_t)64 * KD + (kofs), _d + 8192);                    \
  } while (0)
#define STAGE_B2(dbuf, kofs)                                                 \
  do {                                                                       \
    char* _d = smem + (dbuf) * 32768 + 16384 + dst16;                        \
    async_ld16(Bb + (kofs), _d);                                             \
    async_ld16(Bb + (size_t)64 * KD + (kofs), _d + 8192);                    \
  } while (0)
#define LOAD_A2(cbuf)                                                        \
  do {                                                                       \
    const char* _s = smem + (cbuf) * 32768 + arow;                           \
    _Pragma("unroll") for (int _i = 0; _i < 2; ++_i) {                       \
      a[_i][0] = *(const bf16x8*)(_s + _i * 2048 + cs0);                     \
      a[_i][1] = *(const bf16x8*)(_s + _i * 2048 + cs1);                     \
    }                                                                        \
  } while (0)
#define LOAD_B2(cbuf)                                                        \
  do {                                                                       \
    const char* _s = smem + (cbuf) * 32768 + 16384 + brow;                   \
    _Pragma("unroll") for (int _j = 0; _j < 4; ++_j) {                       \
      b[_j][0] = *(const bf16x8*)(_s + _j * 2048 + cs0);                     \
      b[_j][1] = *(const bf16x8*)(_s + _j * 2048 + cs1);                     \
    }                                                                        \
  } while (0)
#define MMA2                                                                 \
  do {                                                                       \
    _Pragma("unroll") for (int _i = 0; _i < 2; ++_i)                         \
    _Pragma("unroll") for (int _j = 0; _j < 4; ++_j) {                       \
      acc[_i][_j] = __builtin_amdgcn_mfma_f32_16x16x32_bf16(                 \
          a[_i][0], b[_j][0], acc[_i][_j], 0, 0, 0);                         \
      acc[_i][_j] = __builtin_amdgcn_mfma_f32_16x16x32_bf16(                 \
          a[_i][1], b[_j][1], acc[_i][_j], 0, 0, 0);                         \
    }                                                                        \
  } while (0)

  constexpr int NT = KD / 64;

  // prologue: stage tile 0 (4 loads)
  STAGE_A2(0, 0);
  STAGE_B2(0, 0);

  int c = 0;
  for (int tk = 1; tk < NT; ++tk) {
    const int kn = tk * 64;
    const int d = c ^ 1;
    STAGE_A2(d, kn);            // outstanding 4 -> 8
    STAGE_B2(d, kn);
    WAIT_VM(4);                 // retire exactly the previous tile's 4 loads
    BARRIER;
    LOAD_A2(c);
    LOAD_B2(c);
    WAIT_LGKM;
    __builtin_amdgcn_s_setprio(1);
    MMA2;
    __builtin_amdgcn_s_setprio(0);
    BARRIER;                    // WAR before next iter writes buf c
    c = d;
  }

  WAIT_VM(0);
  BARRIER;
  LOAD_A2(c);
  LOAD_B2(c);
  WAIT_LGKM;
  MMA2;

  // epilogue: scatter rows via row_dst, +bias +pos_emb +seq_emb (f32 out)
#pragma unroll
  for (int i = 0; i < 2; ++i) {
    int mbase = m0 + wm * 32 + i * 16 + l4 * 4;     // local row
#pragma unroll
    for (int q = 0; q < 4; ++q) {
      int r = mbase + q;                            // local row
      if (row_base + r >= M) continue;
      int dst = row_dst[row_base + r];              // (b*S+s)*L + slot
      int slot = dst & (NL - 1);
      int sg = (dst >> 8) & 3;
#pragma unroll
      for (int j = 0; j < 4; ++j) {
        int n = n0 + wn * 64 + j * 16 + l15;
        float v = acc[i][j][q] + bias[n] + pos_emb[slot * ND + n] +
                  seq_emb[(sg + 1) * ND + n];
        out[(size_t)dst * ND + n] = v;              // f32 output
      }
    }
  }
#undef STAGE_A2
#undef STAGE_B2
#undef LOAD_A2
#undef LOAD_B2
#undef MMA2
}

// ---------------------------------------------------------------------------
// K5: background fill (f32) — zeros for unkept slots, empty-group slot 0,
// and the f32 sequence mask. One block per (b, s).
// ---------------------------------------------------------------------------
__global__ void fill_bg_kernel(const int* __restrict__ kept_eff,
                               const float* __restrict__ empty_tokens,
                               const float* __restrict__ pos_emb,
                               const float* __restrict__ seq_emb,
                               float* __restrict__ out,
                               float* __restrict__ mask) {
  int g = blockIdx.x;              // b*S + s
  int s = g & 3;
  int t = threadIdx.x;
  int ce = kept_eff[g];            // min(count, L)
  bool empty = (ce == 0);
  int keptm = empty ? 1 : ce;

  mask[g * NL + t] = (t < keptm) ? 1.f : 0.f;      // t in [0,256)=L

  float* base = out + (size_t)g * NL * ND;
  if (empty) {
    for (int d = t; d < ND; d += 256)
      base[d] = empty_tokens[s * ND + d] + pos_emb[d] + seq_emb[(s + 1) * ND + d];
  }
  int start = empty ? 1 : ce;
  // zero-fill slots [start, 256) with 16B stores
  uint4* p = (uint4*)base;         // 4 f32 per uint4; one slot = 128 uint4
  uint4 z; z.x = z.y = z.z = z.w = 0u;
  for (int i = start * (ND / 4) + t; i < NL * (ND / 4); i += 256) p[i] = z;
}

// ---------------------------------------------------------------------------
extern "C" void kernel_launch(void* const* d_in, const int* in_sizes, int n_in,
                              void* d_out, int out_size, void* d_ws,
                              size_t ws_size, hipStream_t stream) {
  const float* embed_table = (const float*)d_in[0];
  const float* time_gap_emb = (const float*)d_in[1];
  const float* seq_id_emb = (const float*)d_in[2];
  const float* pos_emb = (const float*)d_in[3];
  const float* ln_gamma = (const float*)d_in[4];
  const float* ln_beta = (const float*)d_in[5];
  const float* w1 = (const float*)d_in[6];
  const float* b1 = (const float*)d_in[7];
  const float* w2 = (const float*)d_in[8];
  const float* b2 = (const float*)d_in[9];
  const float* empty_tokens = (const float*)d_in[10];
  const int* history_tokens = (const int*)d_in[11];
  const int* post_tokens = (const int*)d_in[12];
  const int* author_tokens = (const int*)d_in[13];
  const int* action_tokens = (const int*)d_in[14];
  const int* time_gap = (const int*)d_in[15];
  const int* group_ids = (const int*)d_in[16];
  const int* lengths = (const int*)d_in[17];

  // Workspace (~88 MB peak)
  char* ws = (char*)d_ws;
  int* n_rows = (int*)ws;                                  // 4 B
  int* kept_eff = (int*)(ws + 256);                        // 128*4 B
  int* row_src = (int*)(ws + 4096);                        // 32768*4 B
  int* row_dst = (int*)(ws + 4096 + 131072);               // 32768*4 B
  bf16_t* W1T = (bf16_t*)(ws + 266240);                    // [2048][2560] bf16
  bf16_t* W2T = W1T + (size_t)HID * FIVE_D;                // [512][2048]  bf16
  bf16_t* Xc = W2T + (size_t)ND * HID;                     // [CHUNK][2560] bf16
  bf16_t* H1c = Xc + (size_t)CHUNK * FIVE_D;               // [CHUNK][2048] bf16

  float* out_states = (float*)d_out;                       // f32 output
  float* out_mask = out_states + (size_t)NB * NS * NL * ND;

  // Dynamic-LDS opt-in for the two GEMMs.  Host-side, idempotent, called
  // unconditionally every launch (no call-count-dependent branching).
  (void)hipFuncSetAttribute(
      reinterpret_cast<const void*>(gemm256_kernel<FIVE_D, HID>),
      hipFuncAttributeMaxDynamicSharedMemorySize, 131072);
  (void)hipFuncSetAttribute(
      reinterpret_cast<const void*>(gemm128_scatter_kernel<HID>),
      hipFuncAttributeMaxDynamicSharedMemorySize, 65536);

  // n_rows must start at 0 (ws is poisoned 0xAA before every launch).
  hipMemsetAsync(n_rows, 0, 4, stream);

  build_index_kernel<<<NB * NS, 256, 0, stream>>>(group_ids, lengths, n_rows,
                                                  kept_eff, row_src, row_dst);

  transpose_cvt_kernel<FIVE_D, HID>
      <<<dim3(HID / 32, FIVE_D / 32), 256, 0, stream>>>(w1, W1T);
  transpose_cvt_kernel<HID, ND>
      <<<dim3(ND / 32, HID / 32), 256, 0, stream>>>(w2, W2T);

  for (int c = 0; c < NCHUNK; ++c) {
    int row_base = c * CHUNK;
    gather_ln_kernel<<<CHUNK, 256, 0, stream>>>(
        embed_table, time_gap_emb, history_tokens, post_tokens, author_tokens,
        action_tokens, time_gap, ln_gamma, ln_beta, n_rows, row_src, row_base,
        Xc);

    gemm256_kernel<FIVE_D, HID>
        <<<dim3(HID / 256, CHUNK / 256), 512, 131072, stream>>>(
            Xc, W1T, n_rows, row_base, b1, H1c);

    gemm128_scatter_kernel<HID>
        <<<dim3(ND / 128, CHUNK / 128), 512, 65536, stream>>>(
            H1c, W2T, n_rows, row_base, b2, row_dst, pos_emb, seq_id_emb,
            out_states);
  }

  fill_bg_kernel<<<NB * NS, 256, 0, stream>>>(kept_eff, empty_tokens, pos_emb,
                                              seq_id_emb, out_states, out_mask);
}

// Round 4
// 449.277 us; speedup vs baseline: 1.1752x; 1.0547x over previous
//
#include <hip/hip_runtime.h>
#include <hip/hip_bf16.h>
#include <stdint.h>

// Problem constants
#define NB 32
#define NL 256
#define NS 4
#define ND 512
#define NH 1024           // NL * NS
#define FIVE_D 2560
#define HID 2048
#define MMAX 32768        // NB * NS * NL (cap on compact rows)
#define CHUNK 8192        // rows per chunk (workspace ~88 MB)
#define NCHUNK 4

// Inputs: f32 / int32. OUTPUT: f32 (states [B,S,L,D] then mask [B,S,L]).
typedef __bf16 bf16_t;
typedef __bf16 bf16x8 __attribute__((ext_vector_type(8)));
typedef float f32x4 __attribute__((ext_vector_type(4)));

// async global->LDS, 16B per lane (wave-uniform base + lane*16 layout).
__device__ __forceinline__ void async_ld16(const void* g, void* l) {
  __builtin_amdgcn_global_load_lds(
      (__attribute__((address_space(1))) void*)(uintptr_t)g,
      (__attribute__((address_space(3))) void*)(uintptr_t)l, 16, 0, 0);
}

// ---------------------------------------------------------------------------
// K1: build compact row index — PARALLEL version.
// ---------------------------------------------------------------------------
__global__ void build_index_kernel(const int* __restrict__ group_ids,
                                   const int* __restrict__ lengths,
                                   int* __restrict__ n_rows,
                                   int* __restrict__ kept_eff,
                                   int* __restrict__ row_src,
                                   int* __restrict__ row_dst) {
  const int g = blockIdx.x;            // b*NS + s
  const int b = g >> 2, s = g & 3;
  const int t = threadIdx.x;           // 0..255
  const int lane = t & 63, w = t >> 6; // 4 waves
  int len = lengths[b];
  len = len < 0 ? 0 : (len > NH ? NH : len);
  const int* gi = group_ids + b * NH;

  __shared__ int wtot[16];             // per (chunk, wave) match counts
  __shared__ int sbase;

  bool valid[4];
#pragma unroll
  for (int c = 0; c < 4; ++c) {
    int h = c * 256 + t;
    valid[c] = (h < len) && (gi[h] == s + 1);
    unsigned long long m = __ballot(valid[c]);
    if (lane == 0) wtot[c * 4 + w] = __popcll(m);
  }
  __syncthreads();

  int pre[16];
  int run = 0;
#pragma unroll
  for (int i = 0; i < 16; ++i) { pre[i] = run; run += wtot[i]; }
  const int count = run;
  const int keff = count < NL ? count : NL;
  const int offset = count - keff;     // max(count - L, 0)

  if (t == 0) {
    kept_eff[g] = keff;
    sbase = atomicAdd(n_rows, keff);
  }
  __syncthreads();
  const int base = sbase;

  const unsigned long long lt = (1ull << lane) - 1ull;
#pragma unroll
  for (int c = 0; c < 4; ++c) {
    unsigned long long m = __ballot(valid[c]);
    if (valid[c]) {
      int rank = pre[c * 4 + w] + __popcll(m & lt);
      if (rank >= offset) {
        int slot = rank - offset;
        row_src[base + slot] = b * NH + c * 256 + t;
        row_dst[base + slot] = g * NL + slot;
      }
    }
  }
}

// ---------------------------------------------------------------------------
// K2: f32 [K,N] -> bf16 [N,K] tiled transpose (weights).
// ---------------------------------------------------------------------------
template <int KD, int NDIM>
__global__ void transpose_cvt_kernel(const float* __restrict__ src,
                                     bf16_t* __restrict__ dst) {
  __shared__ float tile[32][33];
  int k0 = blockIdx.y * 32, n0 = blockIdx.x * 32;
  int tx = threadIdx.x & 31, ty = threadIdx.x >> 5;   // 32 x 8
#pragma unroll
  for (int i = 0; i < 32; i += 8)
    tile[ty + i][tx] = src[(size_t)(k0 + ty + i) * NDIM + n0 + tx];
  __syncthreads();
#pragma unroll
  for (int i = 0; i < 32; i += 8)
    dst[(size_t)(n0 + ty + i) * KD + k0 + tx] = (bf16_t)tile[tx][ty + i];
}

// ---------------------------------------------------------------------------
// K3: gather 5 f32 embeddings + LayerNorm -> bf16 X[r_local, 2560]
// ---------------------------------------------------------------------------
__global__ void gather_ln_kernel(const float* __restrict__ embed,
                                 const float* __restrict__ tg_emb,
                                 const int* __restrict__ ht,
                                 const int* __restrict__ pt,
                                 const int* __restrict__ at,
                                 const int* __restrict__ ct,
                                 const int* __restrict__ tg,
                                 const float* __restrict__ gamma,
                                 const float* __restrict__ beta,
                                 const int* __restrict__ n_rows,
                                 const int* __restrict__ row_src,
                                 int row_base,
                                 bf16_t* __restrict__ X) {
  int rl = blockIdx.x;
  int r = row_base + rl;
  if (r >= *n_rows) return;
  int pos = row_src[r];
  int t = threadIdx.x;

  const float* seg[5];
  seg[0] = embed + (size_t)ht[pos] * ND;
  seg[1] = embed + (size_t)pt[pos] * ND;
  seg[2] = embed + (size_t)at[pos] * ND;
  seg[3] = embed + (size_t)ct[pos] * ND;
  int tgv = tg[pos];
  tgv = tgv < 0 ? 0 : (tgv > 128 ? 128 : tgv);
  seg[4] = tg_emb + (size_t)tgv * ND;

  float v[10];
  float sum = 0.f, sq = 0.f;
#pragma unroll
  for (int i = 0; i < 10; ++i) {
    int c = t + i * 256;                 // 0..2559; c>>9 constant per i
    v[i] = seg[c >> 9][c & 511];
    sum += v[i];
    sq += v[i] * v[i];
  }
#pragma unroll
  for (int off = 32; off > 0; off >>= 1) {
    sum += __shfl_down(sum, off);
    sq += __shfl_down(sq, off);
  }
  __shared__ float red[8];
  int wv = t >> 6, ln = t & 63;
  if (ln == 0) { red[wv] = sum; red[4 + wv] = sq; }
  __syncthreads();
  float S = red[0] + red[1] + red[2] + red[3];
  float Q = red[4] + red[5] + red[6] + red[7];
  float mu = S * (1.f / FIVE_D);
  float var = Q * (1.f / FIVE_D) - mu * mu;
  float rstd = rsqrtf(var + 1e-5f);

  bf16_t* xr = X + (size_t)rl * FIVE_D;
#pragma unroll
  for (int i = 0; i < 10; ++i) {
    int c = t + i * 256;
    xr[c] = (bf16_t)((v[i] - mu) * rstd * gamma[c] + beta[c]);
  }
}

// ---------------------------------------------------------------------------
// Shared sync macros.  v2 ledger (verified, 89 us): one counted wait per
// K-tile covering the ENTIRE previous-staged tile.  Round-3 lesson: do NOT
// issue prefetch traffic immediately before the wait (fresh loads compete in
// the L2/HBM queues with the loads the wait blocks on — 89->99 us).  A-stage
// rides ahead of the wait (issued previous iteration's distance), B-stage is
// issued right AFTER the wait, early in compute.
//   steady: 8 outstanding -> +4 A -> vmcnt(4) retires prev tile's 8 ->
//   barrier -> compute (issue 4 B early) -> barrier (WAR).
// vmcnt never reaches 0 in the main loop (T4); T2 swizzle + T5 setprio kept.
// NOTE: no explicit lgkmcnt drains — ds_reads here are compiler-visible
// loads, so hipcc emits fine-grained lgkmcnt(N) and can overlap ds_read
// with MFMA within a phase (m97 asm evidence; rule #18 is for asm ds_read).
// ---------------------------------------------------------------------------
#define FENCE asm volatile("" ::: "memory")
#define BARRIER do { FENCE; __builtin_amdgcn_s_barrier(); FENCE; } while (0)
#define WAIT_VM(n) asm volatile("s_waitcnt vmcnt(" #n ")" ::: "memory")

// ---------------------------------------------------------------------------
// K4a: 256x256 MFMA GEMM, counted-vmcnt double-buffered schedule (plain HIP).
// C[M,N] = A[M,KD] @ Bt[N,KD]^T, epilogue bias+SiLU -> bf16 Cb.
// 512 thr = 8 waves (2M x 4N), BK=64, 128 KiB LDS double-buffer.
// ---------------------------------------------------------------------------
template <int KD, int LDC>
__launch_bounds__(512, 2)
__global__ void gemm256_kernel(const bf16_t* __restrict__ A,
                               const bf16_t* __restrict__ Bt,
                               const int* __restrict__ nrows_p,
                               int row_base,
                               const float* __restrict__ bias,
                               bf16_t* __restrict__ Cb) {
  static_assert(KD % 64 == 0 && KD / 64 >= 2, "KD");
  const int M = *nrows_p;
  const int m0 = blockIdx.y * 256;
  if (row_base + m0 >= M) return;
  const int n0 = blockIdx.x * 256;

  extern __shared__ char smem[];   // [2][ A 32KB | B 32KB ] = 128 KiB

  const int t = threadIdx.x;        // 0..511
  const int lane = t & 63;
  const int wv = t >> 6;            // 0..7
  const int wm = wv >> 2;           // 0..1  (M half)
  const int wn = wv & 3;            // 0..3  (N quarter)
  const int l15 = lane & 15;
  const int l4 = lane >> 4;

  // ---- staging mapping: thread t covers linear LDS chunk t (and t+512).
  // chunk c = row r (c>>3) x 16B-slot q (c&7); slot holds global chunk q^(r&7).
  const int r0 = t >> 3;               // 0..63 (j=1 adds 64 rows: (r&7) same)
  const int sq = (t & 7) ^ (r0 & 7);   // inverse-swizzled global chunk
  const bf16_t* Ab = A + (size_t)(m0 + r0) * KD + sq * 8;
  const bf16_t* Bb = Bt + (size_t)(n0 + r0) * KD + sq * 8;
  const int dst16 = t * 16;

  // ---- ds_read lane offsets (fragment row l15, chunk (ks*4+l4)^(l15&7))
  const int cs0 = (l4 ^ (l15 & 7)) << 4;   // ks=0 swizzled byte slot
  const int cs1 = cs0 ^ 64;                // ks=1
  const int arow = (wm * 128 + l15) * 128; // A row byte base for this wave
  const int brow = (wn * 64 + l15) * 128;  // B row byte base

  f32x4 acc[2][2][4][2] = {};              // [mh][nh][i][jj]
  bf16x8 a[4][2], bl[2][2], bh[2][2];

#define STAGE_A(dbuf, h, kofs)                                               \
  do {                                                                       \
    char* _d = smem + (dbuf) * 65536 + (h) * 16384 + dst16;                  \
    async_ld16(Ab + (size_t)((h) * 128) * KD + (kofs), _d);                  \
    async_ld16(Ab + (size_t)((h) * 128 + 64) * KD + (kofs), _d + 8192);      \
  } while (0)
#define STAGE_B(dbuf, h, kofs)                                               \
  do {                                                                       \
    char* _d = smem + (dbuf) * 65536 + 32768 + (h) * 16384 + dst16;          \
    async_ld16(Bb + (size_t)((h) * 128) * KD + (kofs), _d);                  \
    async_ld16(Bb + (size_t)((h) * 128 + 64) * KD + (kofs), _d + 8192);      \
  } while (0)
#define LOAD_A(cbuf, mh)                                                     \
  do {                                                                       \
    const char* _s = smem + (cbuf) * 65536 + (mh) * 8192 + arow;             \
    _Pragma("unroll") for (int _i = 0; _i < 4; ++_i) {                       \
      a[_i][0] = *(const bf16x8*)(_s + _i * 2048 + cs0);                     \
      a[_i][1] = *(const bf16x8*)(_s + _i * 2048 + cs1);                     \
    }                                                                        \
  } while (0)
#define LOAD_B(dst, cbuf, nh)                                                \
  do {                                                                       \
    const char* _s = smem + (cbuf) * 65536 + 32768 + (nh) * 4096 + brow;     \
    _Pragma("unroll") for (int _j = 0; _j < 2; ++_j) {                       \
      dst[_j][0] = *(const bf16x8*)(_s + _j * 2048 + cs0);                   \
      dst[_j][1] = *(const bf16x8*)(_s + _j * 2048 + cs1);                   \
    }                                                                        \
  } while (0)
#define MMA(mh, nh, B)                                                       \
  do {                                                                       \
    _Pragma("unroll") for (int _i = 0; _i < 4; ++_i)                         \
    _Pragma("unroll") for (int _j = 0; _j < 2; ++_j) {                       \
      acc[mh][nh][_i][_j] = __builtin_amdgcn_mfma_f32_16x16x32_bf16(         \
          a[_i][0], B[_j][0], acc[mh][nh][_i][_j], 0, 0, 0);                 \
      acc[mh][nh][_i][_j] = __builtin_amdgcn_mfma_f32_16x16x32_bf16(         \
          a[_i][1], B[_j][1], acc[mh][nh][_i][_j], 0, 0, 0);                 \
    }                                                                        \
  } while (0)

  constexpr int NT = KD / 64;

  // prologue: stage tile 0 into buf 0 (8 loads: Alo, Ahi, Blo, Bhi)
  STAGE_A(0, 0, 0);
  STAGE_A(0, 1, 0);
  STAGE_B(0, 0, 0);
  STAGE_B(0, 1, 0);

  int c = 0;
  for (int tk = 1; tk < NT; ++tk) {  // compute tile tk-1 (buf c), stage tk
    const int kn = tk * 64;
    const int d = c ^ 1;
    // stage A-halves of next tile: outstanding 8 -> 12
    STAGE_A(d, 0, kn);
    STAGE_A(d, 1, kn);
    WAIT_VM(4);      // retire exactly the previous tile's 8 loads (this wave)
    BARRIER;         // join: ALL waves' tile-c loads have landed in LDS
    // quadrant (m-lo, n-lo)
    LOAD_A(c, 0);
    LOAD_B(bl, c, 0);
    __builtin_amdgcn_s_setprio(1);
    MMA(0, 0, bl);
    __builtin_amdgcn_s_setprio(0);
    // stage B-halves of next tile EARLY in compute (after the wait, so this
    // traffic never sits ahead of a blocked wait): outstanding 4 -> 8
    STAGE_B(d, 0, kn);
    STAGE_B(d, 1, kn);
    // quadrant (m-lo, n-hi)
    LOAD_B(bh, c, 1);
    __builtin_amdgcn_s_setprio(1);
    MMA(0, 1, bh);
    __builtin_amdgcn_s_setprio(0);
    // quadrants (m-hi, n-hi) and (m-hi, n-lo)
    LOAD_A(c, 1);
    __builtin_amdgcn_s_setprio(1);
    MMA(1, 1, bh);
    MMA(1, 0, bl);
    __builtin_amdgcn_s_setprio(0);
    BARRIER;         // WAR: all reads of buf c done before tk+1 writes buf c
    c = d;
  }

  // peeled last tile: its 8 loads are the only outstanding ones
  WAIT_VM(0);
  BARRIER;
  LOAD_A(c, 0);
  LOAD_B(bl, c, 0);
  MMA(0, 0, bl);
  LOAD_B(bh, c, 1);
  MMA(0, 1, bh);
  LOAD_A(c, 1);
  MMA(1, 1, bh);
  MMA(1, 0, bl);

  // epilogue: bias + SiLU -> bf16 (rows beyond M are garbage; GEMM2 guards)
#pragma unroll
  for (int mh = 0; mh < 2; ++mh)
#pragma unroll
    for (int i = 0; i < 4; ++i) {
      const int rbase = m0 + wm * 128 + mh * 64 + i * 16 + l4 * 4;
#pragma unroll
      for (int nh = 0; nh < 2; ++nh)
#pragma unroll
        for (int j = 0; j < 2; ++j) {
          const int n = n0 + wn * 64 + nh * 32 + j * 16 + l15;
          const float bn = bias[n];
#pragma unroll
          for (int q = 0; q < 4; ++q) {
            float v = acc[mh][nh][i][j][q] + bn;
            v = v / (1.f + __expf(-v));              // SiLU
            Cb[(size_t)(rbase + q) * LDC + n] = (bf16_t)v;
          }
        }
    }
#undef STAGE_A
#undef STAGE_B
#undef LOAD_A
#undef LOAD_B
#undef MMA
}

// ---------------------------------------------------------------------------
// K4b: 128x128 MFMA GEMM for GEMM2 (N=512), same v2 counted-vmcnt ledger.
// 512 thr = 8 waves (4M x 2N), per-wave 32x64 output, BK=64, 64 KiB LDS
// double-buffer.  Rows are 128 B (64 bf16) exactly like gemm256, so the
// identical st-swizzle math applies (q ^= r&7 per 16B chunk, both sides).
// Epilogue: +bias +pos_emb +seq_emb, scatter f32 rows via row_dst.
// ---------------------------------------------------------------------------
template <int KD>
__launch_bounds__(512, 2)
__global__ void gemm128_scatter_kernel(const bf16_t* __restrict__ A,
                                       const bf16_t* __restrict__ Bt,
                                       const int* __restrict__ nrows_p,
                                       int row_base,
                                       const float* __restrict__ bias,
                                       const int* __restrict__ row_dst,
                                       const float* __restrict__ pos_emb,
                                       const float* __restrict__ seq_emb,
                                       float* __restrict__ out) {
  static_assert(KD % 64 == 0 && KD / 64 >= 2, "KD");
  const int M = *nrows_p;
  const int m0 = blockIdx.y * 128;
  if (row_base + m0 >= M) return;
  const int n0 = blockIdx.x * 128;

  extern __shared__ char smem[];   // [2][ A 16KB | B 16KB ] = 64 KiB

  const int t = threadIdx.x;        // 0..511
  const int lane = t & 63;
  const int wv = t >> 6;            // 0..7
  const int wm = wv >> 1;           // 0..3  (M quarter, 32 rows)
  const int wn = wv & 1;            // 0..1  (N half, 64 cols)
  const int l15 = lane & 15;
  const int l4 = lane >> 4;

  // staging: thread t covers linear LDS chunk t (rows 0..63) and t+512
  // (rows 64..127); (r+64)&7 == r&7, so sq is constant across both issues.
  const int r0 = t >> 3;               // 0..63
  const int sq = (t & 7) ^ (r0 & 7);
  const bf16_t* Ab = A + (size_t)(m0 + r0) * KD + sq * 8;
  const bf16_t* Bb = Bt + (size_t)(n0 + r0) * KD + sq * 8;
  const int dst16 = t * 16;

  const int cs0 = (l4 ^ (l15 & 7)) << 4;   // ks=0 swizzled byte slot
  const int cs1 = cs0 ^ 64;                // ks=1
  const int arow = (wm * 32 + l15) * 128;  // A row byte base for this wave
  const int brow = (wn * 64 + l15) * 128;  // B row byte base

  f32x4 acc[2][4] = {};                    // [i (16-row frag)][j (16-col frag)]
  bf16x8 a[2][2], b[4][2];

#define STAGE_A2(dbuf, kofs)                                                 \
  do {                                                                       \
    char* _d = smem + (dbuf) * 32768 + dst16;                                \
    async_ld16(Ab + (kofs), _d);                                             \
    async_ld16(Ab + (size_t)64 * KD + (kofs), _d + 8192);                    \
  } while (0)
#define STAGE_B2(dbuf, kofs)                                                 \
  do {                                                                       \
    char* _d = smem + (dbuf) * 32768 + 16384 + dst16;                        \
    async_ld16(Bb + (kofs), _d);                                             \
    async_ld16(Bb + (size_t)64 * KD + (kofs), _d + 8192);                    \
  } while (0)
#define LOAD_A2(cbuf)                                                        \
  do {                                                                       \
    const char* _s = smem + (cbuf) * 32768 + arow;                           \
    _Pragma("unroll") for (int _i = 0; _i < 2; ++_i) {                       \
      a[_i][0] = *(const bf16x8*)(_s + _i * 2048 + cs0);                     \
      a[_i][1] = *(const bf16x8*)(_s + _i * 2048 + cs1);                     \
    }                                                                        \
  } while (0)
#define LOAD_B2(cbuf)                                                        \
  do {                                                                       \
    const char* _s = smem + (cbuf) * 32768 + 16384 + brow;                   \
    _Pragma("unroll") for (int _j = 0; _j < 4; ++_j) {                       \
      b[_j][0] = *(const bf16x8*)(_s + _j * 2048 + cs0);                     \
      b[_j][1] = *(const bf16x8*)(_s + _j * 2048 + cs1);                     \
    }                                                                        \
  } while (0)
#define MMA2                                                                 \
  do {                                                                       \
    _Pragma("unroll") for (int _i = 0; _i < 2; ++_i)                         \
    _Pragma("unroll") for (int _j = 0; _j < 4; ++_j) {                       \
      acc[_i][_j] = __builtin_amdgcn_mfma_f32_16x16x32_bf16(                 \
          a[_i][0], b[_j][0], acc[_i][_j], 0, 0, 0);                         \
      acc[_i][_j] = __builtin_amdgcn_mfma_f32_16x16x32_bf16(                 \
          a[_i][1], b[_j][1], acc[_i][_j], 0, 0, 0);                         \
    }                                                                        \
  } while (0)

  constexpr int NT = KD / 64;

  // prologue: stage tile 0 (4 loads)
  STAGE_A2(0, 0);
  STAGE_B2(0, 0);

  int c = 0;
  for (int tk = 1; tk < NT; ++tk) {
    const int kn = tk * 64;
    const int d = c ^ 1;
    STAGE_A2(d, kn);            // outstanding 4 -> 6
    WAIT_VM(2);                 // retire exactly the previous tile's 4 loads
    BARRIER;
    LOAD_A2(c);
    LOAD_B2(c);
    STAGE_B2(d, kn);            // issue B after the wait: 2 -> 4
    __builtin_amdgcn_s_setprio(1);
    MMA2;
    __builtin_amdgcn_s_setprio(0);
    BARRIER;                    // WAR before next iter writes buf c
    c = d;
  }

  WAIT_VM(0);
  BARRIER;
  LOAD_A2(c);
  LOAD_B2(c);
  MMA2;

  // epilogue: scatter rows via row_dst, +bias +pos_emb +seq_emb (f32 out)
#pragma unroll
  for (int i = 0; i < 2; ++i) {
    int mbase = m0 + wm * 32 + i * 16 + l4 * 4;     // local row
#pragma unroll
    for (int q = 0; q < 4; ++q) {
      int r = mbase + q;                            // local row
      if (row_base + r >= M) continue;
      int dst = row_dst[row_base + r];              // (b*S+s)*L + slot
      int slot = dst & (NL - 1);
      int sg = (dst >> 8) & 3;
#pragma unroll
      for (int j = 0; j < 4; ++j) {
        int n = n0 + wn * 64 + j * 16 + l15;
        float v = acc[i][j][q] + bias[n] + pos_emb[slot * ND + n] +
                  seq_emb[(sg + 1) * ND + n];
        out[(size_t)dst * ND + n] = v;              // f32 output
      }
    }
  }
#undef STAGE_A2
#undef STAGE_B2
#undef LOAD_A2
#undef LOAD_B2
#undef MMA2
}

// ---------------------------------------------------------------------------
// K5: background fill (f32) — zeros for unkept slots, empty-group slot 0,
// and the f32 sequence mask. One block per (b, s).
// ---------------------------------------------------------------------------
__global__ void fill_bg_kernel(const int* __restrict__ kept_eff,
                               const float* __restrict__ empty_tokens,
                               const float* __restrict__ pos_emb,
                               const float* __restrict__ seq_emb,
                               float* __restrict__ out,
                               float* __restrict__ mask) {
  int g = blockIdx.x;              // b*S + s
  int s = g & 3;
  int t = threadIdx.x;
  int ce = kept_eff[g];            // min(count, L)
  bool empty = (ce == 0);
  int keptm = empty ? 1 : ce;

  mask[g * NL + t] = (t < keptm) ? 1.f : 0.f;      // t in [0,256)=L

  float* base = out + (size_t)g * NL * ND;
  if (empty) {
    for (int d = t; d < ND; d += 256)
      base[d] = empty_tokens[s * ND + d] + pos_emb[d] + seq_emb[(s + 1) * ND + d];
  }
  int start = empty ? 1 : ce;
  // zero-fill slots [start, 256) with 16B stores
  uint4* p = (uint4*)base;         // 4 f32 per uint4; one slot = 128 uint4
  uint4 z; z.x = z.y = z.z = z.w = 0u;
  for (int i = start * (ND / 4) + t; i < NL * (ND / 4); i += 256) p[i] = z;
}

// ---------------------------------------------------------------------------
extern "C" void kernel_launch(void* const* d_in, const int* in_sizes, int n_in,
                              void* d_out, int out_size, void* d_ws,
                              size_t ws_size, hipStream_t stream) {
  const float* embed_table = (const float*)d_in[0];
  const float* time_gap_emb = (const float*)d_in[1];
  const float* seq_id_emb = (const float*)d_in[2];
  const float* pos_emb = (const float*)d_in[3];
  const float* ln_gamma = (const float*)d_in[4];
  const float* ln_beta = (const float*)d_in[5];
  const float* w1 = (const float*)d_in[6];
  const float* b1 = (const float*)d_in[7];
  const float* w2 = (const float*)d_in[8];
  const float* b2 = (const float*)d_in[9];
  const float* empty_tokens = (const float*)d_in[10];
  const int* history_tokens = (const int*)d_in[11];
  const int* post_tokens = (const int*)d_in[12];
  const int* author_tokens = (const int*)d_in[13];
  const int* action_tokens = (const int*)d_in[14];
  const int* time_gap = (const int*)d_in[15];
  const int* group_ids = (const int*)d_in[16];
  const int* lengths = (const int*)d_in[17];

  // Workspace (~88 MB peak)
  char* ws = (char*)d_ws;
  int* n_rows = (int*)ws;                                  // 4 B
  int* kept_eff = (int*)(ws + 256);                        // 128*4 B
  int* row_src = (int*)(ws + 4096);                        // 32768*4 B
  int* row_dst = (int*)(ws + 4096 + 131072);               // 32768*4 B
  bf16_t* W1T = (bf16_t*)(ws + 266240);                    // [2048][2560] bf16
  bf16_t* W2T = W1T + (size_t)HID * FIVE_D;                // [512][2048]  bf16
  bf16_t* Xc = W2T + (size_t)ND * HID;                     // [CHUNK][2560] bf16
  bf16_t* H1c = Xc + (size_t)CHUNK * FIVE_D;               // [CHUNK][2048] bf16

  float* out_states = (float*)d_out;                       // f32 output
  float* out_mask = out_states + (size_t)NB * NS * NL * ND;

  // Dynamic-LDS opt-in for the two GEMMs.  Host-side, idempotent, called
  // unconditionally every launch (no call-count-dependent branching).
  (void)hipFuncSetAttribute(
      reinterpret_cast<const void*>(gemm256_kernel<FIVE_D, HID>),
      hipFuncAttributeMaxDynamicSharedMemorySize, 131072);
  (void)hipFuncSetAttribute(
      reinterpret_cast<const void*>(gemm128_scatter_kernel<HID>),
      hipFuncAttributeMaxDynamicSharedMemorySize, 65536);

  // n_rows must start at 0 (ws is poisoned 0xAA before every launch).
  hipMemsetAsync(n_rows, 0, 4, stream);

  build_index_kernel<<<NB * NS, 256, 0, stream>>>(group_ids, lengths, n_rows,
                                                  kept_eff, row_src, row_dst);

  transpose_cvt_kernel<FIVE_D, HID>
      <<<dim3(HID / 32, FIVE_D / 32), 256, 0, stream>>>(w1, W1T);
  transpose_cvt_kernel<HID, ND>
      <<<dim3(ND / 32, HID / 32), 256, 0, stream>>>(w2, W2T);

  for (int c = 0; c < NCHUNK; ++c) {
    int row_base = c * CHUNK;
    gather_ln_kernel<<<CHUNK, 256, 0, stream>>>(
        embed_table, time_gap_emb, history_tokens, post_tokens, author_tokens,
        action_tokens, time_gap, ln_gamma, ln_beta, n_rows, row_src, row_base,
        Xc);

    gemm256_kernel<FIVE_D, HID>
        <<<dim3(HID / 256, CHUNK / 256), 512, 131072, stream>>>(
            Xc, W1T, n_rows, row_base, b1, H1c);

    gemm128_scatter_kernel<HID>
        <<<dim3(ND / 128, CHUNK / 128), 512, 65536, stream>>>(
            H1c, W2T, n_rows, row_base, b2, row_dst, pos_emb, seq_id_emb,
            out_states);
  }

  fill_bg_kernel<<<NB * NS, 256, 0, stream>>>(kept_eff, empty_tokens, pos_emb,
                                              seq_id_emb, out_states, out_mask);
}

// Round 5
// 414.261 us; speedup vs baseline: 1.2745x; 1.0845x over previous
//
#include <hip/hip_runtime.h>
#include <hip/hip_bf16.h>
#include <stdint.h>

// Problem constants
#define NB 32
#define NL 256
#define NS 4
#define ND 512
#define NH 1024           // NL * NS
#define FIVE_D 2560
#define HID 2048
#define MMAX 32768        // NB * NS * NL (cap on compact rows)

// Inputs: f32 / int32. OUTPUT: f32 (states [B,S,L,D] then mask [B,S,L]).
typedef __bf16 bf16_t;
typedef __bf16 bf16x4 __attribute__((ext_vector_type(4)));
typedef __bf16 bf16x8 __attribute__((ext_vector_type(8)));
typedef float f32x4 __attribute__((ext_vector_type(4)));

// async global->LDS, 16B per lane (wave-uniform base + lane*16 layout).
__device__ __forceinline__ void async_ld16(const void* g, void* l) {
  __builtin_amdgcn_global_load_lds(
      (__attribute__((address_space(1))) void*)(uintptr_t)g,
      (__attribute__((address_space(3))) void*)(uintptr_t)l, 16, 0, 0);
}

// ---------------------------------------------------------------------------
// K1: build compact row index + background fill + mask (merged fill_bg).
// One block per (b, s) group; 256 threads; ballot-based rank computation.
// Background slots [keff,256) and empty-group slot 0 are DISJOINT from the
// rows gemm128 scatters ([0,keff)), so fill can run first.
// ---------------------------------------------------------------------------
__global__ void build_index_kernel(const int* __restrict__ group_ids,
                                   const int* __restrict__ lengths,
                                   int* __restrict__ n_rows,
                                   int* __restrict__ row_src,
                                   int* __restrict__ row_dst,
                                   const float* __restrict__ empty_tokens,
                                   const float* __restrict__ pos_emb,
                                   const float* __restrict__ seq_emb,
                                   float* __restrict__ out,
                                   float* __restrict__ mask) {
  const int g = blockIdx.x;            // b*NS + s
  const int b = g >> 2, s = g & 3;
  const int t = threadIdx.x;           // 0..255
  const int lane = t & 63, w = t >> 6; // 4 waves
  int len = lengths[b];
  len = len < 0 ? 0 : (len > NH ? NH : len);
  const int* gi = group_ids + b * NH;

  __shared__ int wtot[16];             // per (chunk, wave) match counts
  __shared__ int sbase;

  bool valid[4];
#pragma unroll
  for (int c = 0; c < 4; ++c) {
    int h = c * 256 + t;
    valid[c] = (h < len) && (gi[h] == s + 1);
    unsigned long long m = __ballot(valid[c]);
    if (lane == 0) wtot[c * 4 + w] = __popcll(m);
  }
  __syncthreads();

  int pre[16];
  int run = 0;
#pragma unroll
  for (int i = 0; i < 16; ++i) { pre[i] = run; run += wtot[i]; }
  const int count = run;
  const int keff = count < NL ? count : NL;
  const int offset = count - keff;     // max(count - L, 0)

  if (t == 0) sbase = atomicAdd(n_rows, keff);
  __syncthreads();
  const int base = sbase;

  const unsigned long long lt = (1ull << lane) - 1ull;
#pragma unroll
  for (int c = 0; c < 4; ++c) {
    unsigned long long m = __ballot(valid[c]);
    if (valid[c]) {
      int rank = pre[c * 4 + w] + __popcll(m & lt);
      if (rank >= offset) {
        int slot = rank - offset;
        row_src[base + slot] = b * NH + c * 256 + t;
        row_dst[base + slot] = g * NL + slot;
      }
    }
  }

  // ---- merged background fill (was fill_bg_kernel) ----
  const bool empty = (count == 0);
  const int keptm = empty ? 1 : keff;
  mask[g * NL + t] = (t < keptm) ? 1.f : 0.f;      // t in [0,256)=L

  float* basep = out + (size_t)g * NL * ND;
  if (empty) {
    for (int d = t; d < ND; d += 256)
      basep[d] = empty_tokens[s * ND + d] + pos_emb[d] +
                 seq_emb[(s + 1) * ND + d];
  }
  int start = empty ? 1 : keff;
  uint4* p = (uint4*)basep;        // one slot = 128 uint4
  uint4 z; z.x = z.y = z.z = z.w = 0u;
  for (int i = start * (ND / 4) + t; i < NL * (ND / 4); i += 256) p[i] = z;
}

// ---------------------------------------------------------------------------
// K2: f32 [K,N] -> bf16 [N,K] tiled transpose (weights).
// ---------------------------------------------------------------------------
template <int KD, int NDIM>
__global__ void transpose_cvt_kernel(const float* __restrict__ src,
                                     bf16_t* __restrict__ dst) {
  __shared__ float tile[32][33];
  int k0 = blockIdx.y * 32, n0 = blockIdx.x * 32;
  int tx = threadIdx.x & 31, ty = threadIdx.x >> 5;   // 32 x 8
#pragma unroll
  for (int i = 0; i < 32; i += 8)
    tile[ty + i][tx] = src[(size_t)(k0 + ty + i) * NDIM + n0 + tx];
  __syncthreads();
#pragma unroll
  for (int i = 0; i < 32; i += 8)
    dst[(size_t)(n0 + ty + i) * KD + k0 + tx] = (bf16_t)tile[tx][ty + i];
}

// ---------------------------------------------------------------------------
// K3: gather 5 f32 embeddings + LayerNorm -> bf16 X[r_local, 2560]
// float4 gathers (16 B/lane, was 4 B/lane scalar), bf16x4 stores,
// grid-stride over rows (no giant early-return sweep).
// Row split across 256 threads: 640 float4 = idx t (seg 0-1), 256+t (seg 2-3),
// 512+t for t<128 (seg 4 = tg_emb).  seg = idx>>7, offset = (idx&127)*4.
// ---------------------------------------------------------------------------
__global__ void gather_ln_kernel(const float* __restrict__ embed,
                                 const float* __restrict__ tg_emb,
                                 const int* __restrict__ ht,
                                 const int* __restrict__ pt,
                                 const int* __restrict__ at,
                                 const int* __restrict__ ct,
                                 const int* __restrict__ tg,
                                 const float* __restrict__ gamma,
                                 const float* __restrict__ beta,
                                 const int* __restrict__ n_rows,
                                 const int* __restrict__ row_src,
                                 int row_base, int chunk,
                                 bf16_t* __restrict__ X) {
  const int t = threadIdx.x;
  const int M = *n_rows;
  int lim = row_base + chunk;
  if (lim > M) lim = M;

  __shared__ float red[8];

  const int i0 = t;                    // f4 idx 0..255   (seg 0..1)
  const int i1 = 256 + t;              // f4 idx 256..511 (seg 2..3)
  const int i2 = 512 + t;              // f4 idx 512..639 (seg 4), t<128 only
  const int s0 = i0 >> 7, o0 = (i0 & 127) * 4;
  const int s1 = i1 >> 7, o1 = (i1 & 127) * 4;
  const int o2 = (i2 & 127) * 4;
  const bool has2 = (t < 128);

  for (int r = row_base + blockIdx.x; r < lim; r += gridDim.x) {
    const int rl = r - row_base;
    const int pos = row_src[r];

    const float* seg[5];
    seg[0] = embed + (size_t)ht[pos] * ND;
    seg[1] = embed + (size_t)pt[pos] * ND;
    seg[2] = embed + (size_t)at[pos] * ND;
    seg[3] = embed + (size_t)ct[pos] * ND;
    int tgv = tg[pos];
    tgv = tgv < 0 ? 0 : (tgv > 128 ? 128 : tgv);
    seg[4] = tg_emb + (size_t)tgv * ND;

    float4 v0 = *(const float4*)(seg[s0] + o0);
    float4 v1 = *(const float4*)(seg[s1] + o1);
    float4 v2 = make_float4(0.f, 0.f, 0.f, 0.f);
    if (has2) v2 = *(const float4*)(seg[4] + o2);

    float sum = v0.x + v0.y + v0.z + v0.w + v1.x + v1.y + v1.z + v1.w +
                v2.x + v2.y + v2.z + v2.w;
    float sq = v0.x * v0.x + v0.y * v0.y + v0.z * v0.z + v0.w * v0.w +
               v1.x * v1.x + v1.y * v1.y + v1.z * v1.z + v1.w * v1.w +
               v2.x * v2.x + v2.y * v2.y + v2.z * v2.z + v2.w * v2.w;
#pragma unroll
    for (int off = 32; off > 0; off >>= 1) {
      sum += __shfl_down(sum, off);
      sq += __shfl_down(sq, off);
    }
    int wv = t >> 6, ln = t & 63;
    if (ln == 0) { red[wv] = sum; red[4 + wv] = sq; }
    __syncthreads();
    float S = red[0] + red[1] + red[2] + red[3];
    float Q = red[4] + red[5] + red[6] + red[7];
    float mu = S * (1.f / FIVE_D);
    float var = Q * (1.f / FIVE_D) - mu * mu;
    float rstd = rsqrtf(var + 1e-5f);

    bf16_t* xr = X + (size_t)rl * FIVE_D;
    {
      float4 gm = *(const float4*)(gamma + i0 * 4);
      float4 bt = *(const float4*)(beta + i0 * 4);
      bf16x4 wv4;
      wv4[0] = (bf16_t)((v0.x - mu) * rstd * gm.x + bt.x);
      wv4[1] = (bf16_t)((v0.y - mu) * rstd * gm.y + bt.y);
      wv4[2] = (bf16_t)((v0.z - mu) * rstd * gm.z + bt.z);
      wv4[3] = (bf16_t)((v0.w - mu) * rstd * gm.w + bt.w);
      *(bf16x4*)(xr + i0 * 4) = wv4;
    }
    {
      float4 gm = *(const float4*)(gamma + i1 * 4);
      float4 bt = *(const float4*)(beta + i1 * 4);
      bf16x4 wv4;
      wv4[0] = (bf16_t)((v1.x - mu) * rstd * gm.x + bt.x);
      wv4[1] = (bf16_t)((v1.y - mu) * rstd * gm.y + bt.y);
      wv4[2] = (bf16_t)((v1.z - mu) * rstd * gm.z + bt.z);
      wv4[3] = (bf16_t)((v1.w - mu) * rstd * gm.w + bt.w);
      *(bf16x4*)(xr + i1 * 4) = wv4;
    }
    if (has2) {
      float4 gm = *(const float4*)(gamma + i2 * 4);
      float4 bt = *(const float4*)(beta + i2 * 4);
      bf16x4 wv4;
      wv4[0] = (bf16_t)((v2.x - mu) * rstd * gm.x + bt.x);
      wv4[1] = (bf16_t)((v2.y - mu) * rstd * gm.y + bt.y);
      wv4[2] = (bf16_t)((v2.z - mu) * rstd * gm.z + bt.z);
      wv4[3] = (bf16_t)((v2.w - mu) * rstd * gm.w + bt.w);
      *(bf16x4*)(xr + i2 * 4) = wv4;
    }
    __syncthreads();   // red[] reused next row
  }
}

// ---------------------------------------------------------------------------
// Shared sync macros.  v4 ledger (verified, 85.7 us): one counted wait per
// K-tile covering the ENTIRE previous-staged tile; A-stage rides ahead of
// the wait (issued last iteration's distance), B-stage issued right AFTER
// the wait, early in compute (round-3 lesson: traffic issued immediately
// before the wait competes with the loads the wait blocks on).
//   steady: 8 outstanding -> +4 A -> vmcnt(4) retires prev tile's 8 ->
//   barrier -> compute (issue 4 B early) -> barrier (WAR).
// vmcnt never reaches 0 in the main loop (T4); T2 swizzle + T5 setprio kept.
// No explicit lgkmcnt drains — ds_reads are compiler-visible loads, hipcc
// emits fine-grained lgkmcnt(N) itself.
// ---------------------------------------------------------------------------
#define FENCE asm volatile("" ::: "memory")
#define BARRIER do { FENCE; __builtin_amdgcn_s_barrier(); FENCE; } while (0)
#define WAIT_VM(n) asm volatile("s_waitcnt vmcnt(" #n ")" ::: "memory")

// ---------------------------------------------------------------------------
// K4a: 256x256 MFMA GEMM, counted-vmcnt double-buffered schedule (plain HIP).
// C[M,N] = A[M,KD] @ Bt[N,KD]^T, epilogue bias+SiLU -> bf16 Cb.
// 512 thr = 8 waves (2M x 4N), BK=64, 128 KiB LDS double-buffer.
// ---------------------------------------------------------------------------
template <int KD, int LDC>
__launch_bounds__(512, 2)
__global__ void gemm256_kernel(const bf16_t* __restrict__ A,
                               const bf16_t* __restrict__ Bt,
                               const int* __restrict__ nrows_p,
                               int row_base,
                               const float* __restrict__ bias,
                               bf16_t* __restrict__ Cb) {
  static_assert(KD % 64 == 0 && KD / 64 >= 2, "KD");
  const int M = *nrows_p;
  const int m0 = blockIdx.y * 256;
  if (row_base + m0 >= M) return;
  const int n0 = blockIdx.x * 256;

  extern __shared__ char smem[];   // [2][ A 32KB | B 32KB ] = 128 KiB

  const int t = threadIdx.x;        // 0..511
  const int lane = t & 63;
  const int wv = t >> 6;            // 0..7
  const int wm = wv >> 2;           // 0..1  (M half)
  const int wn = wv & 3;            // 0..3  (N quarter)
  const int l15 = lane & 15;
  const int l4 = lane >> 4;

  // ---- staging mapping: thread t covers linear LDS chunk t (and t+512).
  // chunk c = row r (c>>3) x 16B-slot q (c&7); slot holds global chunk q^(r&7).
  const int r0 = t >> 3;               // 0..63 (j=1 adds 64 rows: (r&7) same)
  const int sq = (t & 7) ^ (r0 & 7);   // inverse-swizzled global chunk
  const bf16_t* Ab = A + (size_t)(m0 + r0) * KD + sq * 8;
  const bf16_t* Bb = Bt + (size_t)(n0 + r0) * KD + sq * 8;
  const int dst16 = t * 16;

  // ---- ds_read lane offsets (fragment row l15, chunk (ks*4+l4)^(l15&7))
  const int cs0 = (l4 ^ (l15 & 7)) << 4;   // ks=0 swizzled byte slot
  const int cs1 = cs0 ^ 64;                // ks=1
  const int arow = (wm * 128 + l15) * 128; // A row byte base for this wave
  const int brow = (wn * 64 + l15) * 128;  // B row byte base

  f32x4 acc[2][2][4][2] = {};              // [mh][nh][i][jj]
  bf16x8 a[4][2], bl[2][2], bh[2][2];

#define STAGE_A(dbuf, h, kofs)                                               \
  do {                                                                       \
    char* _d = smem + (dbuf) * 65536 + (h) * 16384 + dst16;                  \
    async_ld16(Ab + (size_t)((h) * 128) * KD + (kofs), _d);                  \
    async_ld16(Ab + (size_t)((h) * 128 + 64) * KD + (kofs), _d + 8192);      \
  } while (0)
#define STAGE_B(dbuf, h, kofs)                                               \
  do {                                                                       \
    char* _d = smem + (dbuf) * 65536 + 32768 + (h) * 16384 + dst16;          \
    async_ld16(Bb + (size_t)((h) * 128) * KD + (kofs), _d);                  \
    async_ld16(Bb + (size_t)((h) * 128 + 64) * KD + (kofs), _d + 8192);      \
  } while (0)
#define LOAD_A(cbuf, mh)                                                     \
  do {                                                                       \
    const char* _s = smem + (cbuf) * 65536 + (mh) * 8192 + arow;             \
    _Pragma("unroll") for (int _i = 0; _i < 4; ++_i) {                       \
      a[_i][0] = *(const bf16x8*)(_s + _i * 2048 + cs0);                     \
      a[_i][1] = *(const bf16x8*)(_s + _i * 2048 + cs1);                     \
    }                                                                        \
  } while (0)
#define LOAD_B(dst, cbuf, nh)                                                \
  do {                                                                       \
    const char* _s = smem + (cbuf) * 65536 + 32768 + (nh) * 4096 + brow;     \
    _Pragma("unroll") for (int _j = 0; _j < 2; ++_j) {                       \
      dst[_j][0] = *(const bf16x8*)(_s + _j * 2048 + cs0);                   \
      dst[_j][1] = *(const bf16x8*)(_s + _j * 2048 + cs1);                   \
    }                                                                        \
  } while (0)
#define MMA(mh, nh, B)                                                       \
  do {                                                                       \
    _Pragma("unroll") for (int _i = 0; _i < 4; ++_i)                         \
    _Pragma("unroll") for (int _j = 0; _j < 2; ++_j) {                       \
      acc[mh][nh][_i][_j] = __builtin_amdgcn_mfma_f32_16x16x32_bf16(         \
          a[_i][0], B[_j][0], acc[mh][nh][_i][_j], 0, 0, 0);                 \
      acc[mh][nh][_i][_j] = __builtin_amdgcn_mfma_f32_16x16x32_bf16(         \
          a[_i][1], B[_j][1], acc[mh][nh][_i][_j], 0, 0, 0);                 \
    }                                                                        \
  } while (0)

  constexpr int NT = KD / 64;

  // prologue: stage tile 0 into buf 0 (8 loads: Alo, Ahi, Blo, Bhi)
  STAGE_A(0, 0, 0);
  STAGE_A(0, 1, 0);
  STAGE_B(0, 0, 0);
  STAGE_B(0, 1, 0);

  int c = 0;
  for (int tk = 1; tk < NT; ++tk) {  // compute tile tk-1 (buf c), stage tk
    const int kn = tk * 64;
    const int d = c ^ 1;
    // stage A-halves of next tile: outstanding 8 -> 12
    STAGE_A(d, 0, kn);
    STAGE_A(d, 1, kn);
    WAIT_VM(4);      // retire exactly the previous tile's 8 loads (this wave)
    BARRIER;         // join: ALL waves' tile-c loads have landed in LDS
    // quadrant (m-lo, n-lo)
    LOAD_A(c, 0);
    LOAD_B(bl, c, 0);
    __builtin_amdgcn_s_setprio(1);
    MMA(0, 0, bl);
    __builtin_amdgcn_s_setprio(0);
    // stage B-halves of next tile EARLY in compute (after the wait, so this
    // traffic never sits ahead of a blocked wait): outstanding 4 -> 8
    STAGE_B(d, 0, kn);
    STAGE_B(d, 1, kn);
    // quadrant (m-lo, n-hi)
    LOAD_B(bh, c, 1);
    __builtin_amdgcn_s_setprio(1);
    MMA(0, 1, bh);
    __builtin_amdgcn_s_setprio(0);
    // quadrants (m-hi, n-hi) and (m-hi, n-lo)
    LOAD_A(c, 1);
    __builtin_amdgcn_s_setprio(1);
    MMA(1, 1, bh);
    MMA(1, 0, bl);
    __builtin_amdgcn_s_setprio(0);
    BARRIER;         // WAR: all reads of buf c done before tk+1 writes buf c
    c = d;
  }

  // peeled last tile: its 8 loads are the only outstanding ones
  WAIT_VM(0);
  BARRIER;
  LOAD_A(c, 0);
  LOAD_B(bl, c, 0);
  MMA(0, 0, bl);
  LOAD_B(bh, c, 1);
  MMA(0, 1, bh);
  LOAD_A(c, 1);
  MMA(1, 1, bh);
  MMA(1, 0, bl);

  // epilogue: bias + SiLU -> bf16 (rows beyond M are garbage; GEMM2 guards)
#pragma unroll
  for (int mh = 0; mh < 2; ++mh)
#pragma unroll
    for (int i = 0; i < 4; ++i) {
      const int rbase = m0 + wm * 128 + mh * 64 + i * 16 + l4 * 4;
#pragma unroll
      for (int nh = 0; nh < 2; ++nh)
#pragma unroll
        for (int j = 0; j < 2; ++j) {
          const int n = n0 + wn * 64 + nh * 32 + j * 16 + l15;
          const float bn = bias[n];
#pragma unroll
          for (int q = 0; q < 4; ++q) {
            float v = acc[mh][nh][i][j][q] + bn;
            v = v / (1.f + __expf(-v));              // SiLU
            Cb[(size_t)(rbase + q) * LDC + n] = (bf16_t)v;
          }
        }
    }
#undef STAGE_A
#undef STAGE_B
#undef LOAD_A
#undef LOAD_B
#undef MMA
}

// ---------------------------------------------------------------------------
// K4b: 128x128 MFMA GEMM for GEMM2 (N=512), same v4 counted-vmcnt ledger.
// 512 thr = 8 waves (4M x 2N), per-wave 32x64 output, BK=64, 64 KiB LDS
// double-buffer.  Epilogue: +bias +pos_emb +seq_emb scatter via row_dst.
// ---------------------------------------------------------------------------
template <int KD>
__launch_bounds__(512, 2)
__global__ void gemm128_scatter_kernel(const bf16_t* __restrict__ A,
                                       const bf16_t* __restrict__ Bt,
                                       const int* __restrict__ nrows_p,
                                       int row_base,
                                       const float* __restrict__ bias,
                                       const int* __restrict__ row_dst,
                                       const float* __restrict__ pos_emb,
                                       const float* __restrict__ seq_emb,
                                       float* __restrict__ out) {
  static_assert(KD % 64 == 0 && KD / 64 >= 2, "KD");
  const int M = *nrows_p;
  const int m0 = blockIdx.y * 128;
  if (row_base + m0 >= M) return;
  const int n0 = blockIdx.x * 128;

  extern __shared__ char smem[];   // [2][ A 16KB | B 16KB ] = 64 KiB

  const int t = threadIdx.x;        // 0..511
  const int lane = t & 63;
  const int wv = t >> 6;            // 0..7
  const int wm = wv >> 1;           // 0..3  (M quarter, 32 rows)
  const int wn = wv & 1;            // 0..1  (N half, 64 cols)
  const int l15 = lane & 15;
  const int l4 = lane >> 4;

  const int r0 = t >> 3;               // 0..63
  const int sq = (t & 7) ^ (r0 & 7);
  const bf16_t* Ab = A + (size_t)(m0 + r0) * KD + sq * 8;
  const bf16_t* Bb = Bt + (size_t)(n0 + r0) * KD + sq * 8;
  const int dst16 = t * 16;

  const int cs0 = (l4 ^ (l15 & 7)) << 4;   // ks=0 swizzled byte slot
  const int cs1 = cs0 ^ 64;                // ks=1
  const int arow = (wm * 32 + l15) * 128;  // A row byte base for this wave
  const int brow = (wn * 64 + l15) * 128;  // B row byte base

  f32x4 acc[2][4] = {};                    // [i (16-row frag)][j (16-col frag)]
  bf16x8 a[2][2], b[4][2];

#define STAGE_A2(dbuf, kofs)                                                 \
  do {                                                                       \
    char* _d = smem + (dbuf) * 32768 + dst16;                                \
    async_ld16(Ab + (kofs), _d);                                             \
    async_ld16(Ab + (size_t)64 * KD + (kofs), _d + 8192);                    \
  } while (0)
#define STAGE_B2(dbuf, kofs)                                                 \
  do {                                                                       \
    char* _d = smem + (dbuf) * 32768 + 16384 + dst16;                        \
    async_ld16(Bb + (kofs), _d);                                             \
    async_ld16(Bb + (size_t)64 * KD + (kofs), _d + 8192);                    \
  } while (0)
#define LOAD_A2(cbuf)                                                        \
  do {                                                                       \
    const char* _s = smem + (cbuf) * 32768 + arow;                           \
    _Pragma("unroll") for (int _i = 0; _i < 2; ++_i) {                       \
      a[_i][0] = *(const bf16x8*)(_s + _i * 2048 + cs0);                     \
      a[_i][1] = *(const bf16x8*)(_s + _i * 2048 + cs1);                     \
    }                                                                        \
  } while (0)
#define LOAD_B2(cbuf)                                                        \
  do {                                                                       \
    const char* _s = smem + (cbuf) * 32768 + 16384 + brow;                   \
    _Pragma("unroll") for (int _j = 0; _j < 4; ++_j) {                       \
      b[_j][0] = *(const bf16x8*)(_s + _j * 2048 + cs0);                     \
      b[_j][1] = *(const bf16x8*)(_s + _j * 2048 + cs1);                     \
    }                                                                        \
  } while (0)
#define MMA2                                                                 \
  do {                                                                       \
    _Pragma("unroll") for (int _i = 0; _i < 2; ++_i)                         \
    _Pragma("unroll") for (int _j = 0; _j < 4; ++_j) {                       \
      acc[_i][_j] = __builtin_amdgcn_mfma_f32_16x16x32_bf16(                 \
          a[_i][0], b[_j][0], acc[_i][_j], 0, 0, 0);                         \
      acc[_i][_j] = __builtin_amdgcn_mfma_f32_16x16x32_bf16(                 \
          a[_i][1], b[_j][1], acc[_i][_j], 0, 0, 0);                         \
    }                                                                        \
  } while (0)

  constexpr int NT = KD / 64;

  // prologue: stage tile 0 (4 loads)
  STAGE_A2(0, 0);
  STAGE_B2(0, 0);

  int c = 0;
  for (int tk = 1; tk < NT; ++tk) {
    const int kn = tk * 64;
    const int d = c ^ 1;
    STAGE_A2(d, kn);            // outstanding 4 -> 6
    WAIT_VM(2);                 // retire exactly the previous tile's 4 loads
    BARRIER;
    LOAD_A2(c);
    LOAD_B2(c);
    STAGE_B2(d, kn);            // issue B after the wait: 2 -> 4
    __builtin_amdgcn_s_setprio(1);
    MMA2;
    __builtin_amdgcn_s_setprio(0);
    BARRIER;                    // WAR before next iter writes buf c
    c = d;
  }

  WAIT_VM(0);
  BARRIER;
  LOAD_A2(c);
  LOAD_B2(c);
  MMA2;

  // epilogue: scatter rows via row_dst, +bias +pos_emb +seq_emb (f32 out)
#pragma unroll
  for (int i = 0; i < 2; ++i) {
    int mbase = m0 + wm * 32 + i * 16 + l4 * 4;     // local row
#pragma unroll
    for (int q = 0; q < 4; ++q) {
      int r = mbase + q;                            // local row
      if (row_base + r >= M) continue;
      int dst = row_dst[row_base + r];              // (b*S+s)*L + slot
      int slot = dst & (NL - 1);
      int sg = (dst >> 8) & 3;
#pragma unroll
      for (int j = 0; j < 4; ++j) {
        int n = n0 + wn * 64 + j * 16 + l15;
        float v = acc[i][j][q] + bias[n] + pos_emb[slot * ND + n] +
                  seq_emb[(sg + 1) * ND + n];
        out[(size_t)dst * ND + n] = v;              // f32 output
      }
    }
  }
#undef STAGE_A2
#undef STAGE_B2
#undef LOAD_A2
#undef LOAD_B2
#undef MMA2
}

// ---------------------------------------------------------------------------
extern "C" void kernel_launch(void* const* d_in, const int* in_sizes, int n_in,
                              void* d_out, int out_size, void* d_ws,
                              size_t ws_size, hipStream_t stream) {
  const float* embed_table = (const float*)d_in[0];
  const float* time_gap_emb = (const float*)d_in[1];
  const float* seq_id_emb = (const float*)d_in[2];
  const float* pos_emb = (const float*)d_in[3];
  const float* ln_gamma = (const float*)d_in[4];
  const float* ln_beta = (const float*)d_in[5];
  const float* w1 = (const float*)d_in[6];
  const float* b1 = (const float*)d_in[7];
  const float* w2 = (const float*)d_in[8];
  const float* b2 = (const float*)d_in[9];
  const float* empty_tokens = (const float*)d_in[10];
  const int* history_tokens = (const int*)d_in[11];
  const int* post_tokens = (const int*)d_in[12];
  const int* author_tokens = (const int*)d_in[13];
  const int* action_tokens = (const int*)d_in[14];
  const int* time_gap = (const int*)d_in[15];
  const int* group_ids = (const int*)d_in[16];
  const int* lengths = (const int*)d_in[17];

  // Runtime-adaptive chunking.  ws_size is constant across calls/replays, so
  // this branch is identical on every invocation (graph-capture safe).
  // fixed = index buffers + bf16 weights; per-row = (2560 + 2048) bf16.
  const size_t fixed = 266240 + (size_t)(HID * FIVE_D + ND * HID) * 2;
  int chunk, nchunk;
  if (ws_size >= fixed + (size_t)32768 * 9216) { chunk = 32768; nchunk = 1; }
  else if (ws_size >= fixed + (size_t)16384 * 9216) { chunk = 16384; nchunk = 2; }
  else { chunk = 8192; nchunk = 4; }

  char* ws = (char*)d_ws;
  int* n_rows = (int*)ws;                                  // 4 B
  int* row_src = (int*)(ws + 4096);                        // 32768*4 B
  int* row_dst = (int*)(ws + 4096 + 131072);               // 32768*4 B
  bf16_t* W1T = (bf16_t*)(ws + 266240);                    // [2048][2560] bf16
  bf16_t* W2T = W1T + (size_t)HID * FIVE_D;                // [512][2048]  bf16
  bf16_t* Xc = W2T + (size_t)ND * HID;                     // [chunk][2560] bf16
  bf16_t* H1c = Xc + (size_t)chunk * FIVE_D;               // [chunk][2048] bf16

  float* out_states = (float*)d_out;                       // f32 output
  float* out_mask = out_states + (size_t)NB * NS * NL * ND;

  // Dynamic-LDS opt-in for the two GEMMs.  Host-side, idempotent, called
  // unconditionally every launch (no call-count-dependent branching).
  (void)hipFuncSetAttribute(
      reinterpret_cast<const void*>(gemm256_kernel<FIVE_D, HID>),
      hipFuncAttributeMaxDynamicSharedMemorySize, 131072);
  (void)hipFuncSetAttribute(
      reinterpret_cast<const void*>(gemm128_scatter_kernel<HID>),
      hipFuncAttributeMaxDynamicSharedMemorySize, 65536);

  // n_rows must start at 0 (ws is poisoned 0xAA before every launch).
  hipMemsetAsync(n_rows, 0, 4, stream);

  build_index_kernel<<<NB * NS, 256, 0, stream>>>(
      group_ids, lengths, n_rows, row_src, row_dst, empty_tokens, pos_emb,
      seq_id_emb, out_states, out_mask);

  transpose_cvt_kernel<FIVE_D, HID>
      <<<dim3(HID / 32, FIVE_D / 32), 256, 0, stream>>>(w1, W1T);
  transpose_cvt_kernel<HID, ND>
      <<<dim3(ND / 32, HID / 32), 256, 0, stream>>>(w2, W2T);

  for (int c = 0; c < nchunk; ++c) {
    int row_base = c * chunk;
    gather_ln_kernel<<<2048, 256, 0, stream>>>(
        embed_table, time_gap_emb, history_tokens, post_tokens, author_tokens,
        action_tokens, time_gap, ln_gamma, ln_beta, n_rows, row_src, row_base,
        chunk, Xc);

    gemm256_kernel<FIVE_D, HID>
        <<<dim3(HID / 256, chunk / 256), 512, 131072, stream>>>(
            Xc, W1T, n_rows, row_base, b1, H1c);

    gemm128_scatter_kernel<HID>
        <<<dim3(ND / 128, chunk / 128), 512, 65536, stream>>>(
            H1c, W2T, n_rows, row_base, b2, row_dst, pos_emb, seq_id_emb,
            out_states);
  }
}